// Round 10
// baseline (357.558 us; speedup 1.0000x reference)
//
#include <hip/hip_runtime.h>
#include <hip/hip_bf16.h>

#define N_NODES  100000
#define N_EDGES  1600000
#define N_GRAPHS 2000
#define N_FEAT   13
#define HID      128
#define NB       ((N_NODES + 127) / 128)   // 782 buckets of 128 nodes
#define NBLK     128                        // edge-partition blocks for the sort
#define N2       (NB * NBLK)                // 100096 (bucket,block) windows

typedef __attribute__((ext_vector_type(8))) short bf16x8;   // 8 bf16 = 4 VGPRs
typedef __attribute__((ext_vector_type(4))) float f32x4;
typedef __attribute__((ext_vector_type(8))) unsigned short ushort8;

// ============ contention-free counting sort of edges by dst bucket ============
__global__ void k_hist1(const int* __restrict__ dst, int* __restrict__ counts, int E) {
    __shared__ int hist[NB];
    int k = blockIdx.x, t = threadIdx.x;
    for (int b = t; b < NB; b += 256) hist[b] = 0;
    __syncthreads();
    int epb = (E + NBLK - 1) / NBLK;
    int base = k * epb, lim = min(base + epb, E);
    for (int i = base + t; i < lim; i += 256) atomicAdd(&hist[dst[i] >> 7], 1);
    __syncthreads();
    for (int b = t; b < NB; b += 256) counts[k * NB + b] = hist[b];
}

__global__ void k_transp(const int* __restrict__ counts, int* __restrict__ countsT) {
    int i = blockIdx.x * 256 + threadIdx.x;   // i = b*NBLK + k
    if (i < N2) countsT[i] = counts[(i & (NBLK - 1)) * NB + (i >> 7)];
}

__global__ void k_scatter(const int* __restrict__ src, const int* __restrict__ dst,
                          const int* __restrict__ scT, unsigned int* __restrict__ bstore, int E) {
    __shared__ int cnt[NB];
    int k = blockIdx.x, t = threadIdx.x;
    for (int b = t; b < NB; b += 256) cnt[b] = 0;
    __syncthreads();
    int epb = (E + NBLK - 1) / NBLK;
    int base = k * epb, lim = min(base + epb, E);
    for (int i = base + t; i < lim; i += 256) {
        int d = dst[i];
        int b = d >> 7;
        int r = atomicAdd(&cnt[b], 1);    // LDS rank within (bucket, block) window
        bstore[scT[b * NBLK + k] + r] = ((unsigned int)src[i] << 7) | (unsigned int)(d & 127);
    }
}

// per-bucket node histogram -> indeg + dinv + xs (= dinv * x, padded to 16)
__global__ void k_bhistx(const unsigned int* __restrict__ bstore, const int* __restrict__ scT,
                         const float* __restrict__ x, int* __restrict__ indeg,
                         float* __restrict__ dinv, float* __restrict__ xs, int n, int E) {
    __shared__ int cnt[128];
    int b = blockIdx.x, t = threadIdx.x;
    if (t < 128) cnt[t] = 0;
    __syncthreads();
    int start = scT[b * NBLK];
    int end = (b + 1 < NB) ? scT[(b + 1) * NBLK] : E;
    for (int i = start + t; i < end; i += 256) atomicAdd(&cnt[bstore[i] & 127], 1);
    __syncthreads();
    int node = b * 128 + t;
    if (t < 128 && node < n) {
        int c = cnt[t];
        indeg[node] = c;
        float dv = rsqrtf((float)(c + 1));   // +1 self loop
        dinv[node] = dv;
        float r[16];
#pragma unroll
        for (int k = 0; k < N_FEAT; k++) r[k] = dv * x[node * N_FEAT + k];
        r[13] = r[14] = r[15] = 0.f;
        float4* o = (float4*)&xs[(size_t)node * 16];
        o[0] = float4{r[0], r[1], r[2], r[3]};
        o[1] = float4{r[4], r[5], r[6], r[7]};
        o[2] = float4{r[8], r[9], r[10], r[11]};
        o[3] = float4{r[12], r[13], r[14], r[15]};
    }
}

__global__ void k_bfill(const unsigned int* __restrict__ bstore, const int* __restrict__ scT,
                        const int* __restrict__ off, int* __restrict__ csr, int n, int E) {
    __shared__ int cur[128];
    __shared__ int loff[128];
    int b = blockIdx.x, t = threadIdx.x;
    if (t < 128) {
        cur[t] = 0;
        int node = b * 128 + t;
        loff[t] = (node < n) ? off[node] : 0;
    }
    __syncthreads();
    int start = scT[b * NBLK];
    int end = (b + 1 < NB) ? scT[(b + 1) * NBLK] : E;
    for (int i = start + t; i < end; i += 256) {
        unsigned int e = bstore[i];
        int dl = e & 127;
        int p = loff[dl] + atomicAdd(&cur[dl], 1);
        csr[p] = (int)(e >> 7);
    }
}

// -------------------- scans (exclusive) --------------------
__global__ void k_scan1(const int* __restrict__ in, int* __restrict__ out,
                        int* __restrict__ bsum, int n) {
    __shared__ int ts[256];
    int t = threadIdx.x;
    int base = blockIdx.x * 1024 + t * 4;
    int v0 = (base + 0 < n) ? in[base + 0] : 0;
    int v1 = (base + 1 < n) ? in[base + 1] : 0;
    int v2 = (base + 2 < n) ? in[base + 2] : 0;
    int v3 = (base + 3 < n) ? in[base + 3] : 0;
    int s = v0 + v1 + v2 + v3;
    ts[t] = s;
    __syncthreads();
    for (int o = 1; o < 256; o <<= 1) {
        int x = (t >= o) ? ts[t - o] : 0;
        __syncthreads();
        ts[t] += x;
        __syncthreads();
    }
    if (t == 255) bsum[blockIdx.x] = ts[255];
    int run = ts[t] - s;
    if (base + 0 < n) out[base + 0] = run; run += v0;
    if (base + 1 < n) out[base + 1] = run; run += v1;
    if (base + 2 < n) out[base + 2] = run; run += v2;
    if (base + 3 < n) out[base + 3] = run;
}

__global__ void k_scan_block(const int* __restrict__ in, int* __restrict__ out, int len) {
    __shared__ int ts[256];
    int t = threadIdx.x;
    int v[8];
    int s = 0;
#pragma unroll
    for (int j = 0; j < 8; j++) {
        int i = t * 8 + j;
        v[j] = (i < len) ? in[i] : 0;
        s += v[j];
    }
    ts[t] = s;
    __syncthreads();
    for (int o = 1; o < 256; o <<= 1) {
        int x = (t >= o) ? ts[t - o] : 0;
        __syncthreads();
        ts[t] += x;
        __syncthreads();
    }
    int run = ts[t] - s;
#pragma unroll
    for (int j = 0; j < 8; j++) {
        int i = t * 8 + j;
        if (i < len) out[i] = run;
        run += v[j];
    }
}

__global__ void k_scan3(int* __restrict__ out, const int* __restrict__ bpre, int n) {
    int i = blockIdx.x * 256 + threadIdx.x;
    if (i < n) out[i] += bpre[i >> 10];
}

// -------------------- fp32 -> bf16 RTNE --------------------
__device__ __forceinline__ unsigned short f2bf(float f) {
    unsigned int b = __float_as_uint(f);
    b += 0x7fffu + ((b >> 16) & 1u);
    return (unsigned short)(b >> 16);
}

__device__ __forceinline__ void addrow8(float (&a)[8], uint4 v) {
    a[0] += __uint_as_float(v.x << 16);
    a[1] += __uint_as_float(v.x & 0xffff0000u);
    a[2] += __uint_as_float(v.y << 16);
    a[3] += __uint_as_float(v.y & 0xffff0000u);
    a[4] += __uint_as_float(v.z << 16);
    a[5] += __uint_as_float(v.z & 0xffff0000u);
    a[6] += __uint_as_float(v.w << 16);
    a[7] += __uint_as_float(v.w & 0xffff0000u);
}

// ---------- W1,W2 (fp32 [K][N] row-major) -> Wt (bf16 [N][K]) in one launch ----------
__global__ void k_wcast2(const float* __restrict__ W1, const float* __restrict__ W2,
                         unsigned short* __restrict__ Wt1, unsigned short* __restrict__ Wt2) {
    int i = blockIdx.x * 256 + threadIdx.x;
    if (i < HID * HID) {
        int c = i >> 7, k = i & 127;
        Wt1[i] = f2bf(W1[k * HID + c]);
        Wt2[i] = f2bf(W2[k * HID + c]);
    }
}

// MFMA tail shared by the fused kernels: h (LDS, swizzled bf16 [64][128]) @ Wt -> u (bf16)
// wave = one 16-row tile; A-frag ds_read_b128 swizzled (2-way conflict = free).
__device__ __forceinline__ void mfma_tail(const unsigned short* hl, const unsigned short* Wt,
                                          const float* dinv, unsigned short* u, int nb, int n,
                                          int t) {
    int wave = t >> 6, lane = t & 63;
    int lrow = lane & 15, kq = lane >> 4;
    f32x4 acc[8];
#pragma unroll
    for (int ct = 0; ct < 8; ct++) acc[ct] = f32x4{0.f, 0.f, 0.f, 0.f};
#pragma unroll
    for (int s = 0; s < 4; s++) {
        int row = wave * 16 + lrow;
        int boff = (row * 256 + s * 64 + kq * 16) ^ ((lrow & 7) << 4);
        bf16x8 afr = *(const bf16x8*)((const char*)hl + boff);
#pragma unroll
        for (int ct = 0; ct < 8; ct++) {
            bf16x8 bfr = *(const bf16x8*)&Wt[(ct * 16 + lrow) * HID + s * 32 + kq * 8];
            acc[ct] = __builtin_amdgcn_mfma_f32_16x16x32_bf16(afr, bfr, acc[ct], 0, 0, 0);
        }
    }
#pragma unroll
    for (int r = 0; r < 4; r++) {
        int node = nb + wave * 16 + kq * 4 + r;   // D: row=(lane>>4)*4+r, col=lrow
        if (node < n) {
            float dv = dinv[node];
#pragma unroll
            for (int ct = 0; ct < 8; ct++)
                u[(size_t)node * HID + ct * 16 + lrow] = f2bf(dv * acc[ct][r]);
        }
    }
}

// ---- fused layer0+GEMM1: gather13 -> h0=relu(agg@W0+b0) in LDS -> MFMA Wt1 -> u1 ----
__global__ __launch_bounds__(256) void k_gf13m(const float* __restrict__ xs,
                                               const int* __restrict__ off,
                                               const int* __restrict__ indeg,
                                               const int* __restrict__ csr,
                                               const float* __restrict__ dinv,
                                               const float* __restrict__ W,
                                               const float* __restrict__ b,
                                               const unsigned short* __restrict__ Wt1,
                                               unsigned short* __restrict__ u1, int n) {
    __shared__ float Ws[N_FEAT * HID];
    __shared__ float bs[HID];
    __shared__ __align__(16) float aggs[64][16];
    __shared__ __align__(16) unsigned short hl[64 * 128];   // swizzled bf16
    int t = threadIdx.x;
    for (int i = t; i < N_FEAT * HID; i += 256) Ws[i] = W[i];
    if (t < HID) bs[t] = b[t];
    int lane = t & 63;
    int slot = (t >> 6) * 16 + (lane >> 2);   // node slot 0..63
    int l2 = lane & 3;
    int nb = blockIdx.x * 64;
    int d = nb + slot;
    const float4* X4 = (const float4*)xs;
    if (d < n) {
        int s0 = off[d], c = indeg[d];
        float4 acc = X4[(size_t)d * 4 + l2];   // self term (dinv[d]-scaled)
        int p = 0;
        for (; p + 7 < c; p += 8) {
            int s_[8];
#pragma unroll
            for (int j = 0; j < 8; j++) s_[j] = csr[s0 + p + j];
            float4 v[8];
#pragma unroll
            for (int j = 0; j < 8; j++) v[j] = X4[(size_t)s_[j] * 4 + l2];
#pragma unroll
            for (int j = 0; j < 8; j++) {
                acc.x += v[j].x; acc.y += v[j].y; acc.z += v[j].z; acc.w += v[j].w;
            }
        }
        for (; p < c; p++) {
            float4 v = X4[(size_t)csr[s0 + p] * 4 + l2];
            acc.x += v.x; acc.y += v.y; acc.z += v.z; acc.w += v.w;
        }
        float dv = dinv[d];
        float4 r = {dv * acc.x, dv * acc.y, dv * acc.z, dv * acc.w};
        *(float4*)&aggs[slot][l2 * 4] = r;
    }
    __syncthreads();
    // h0 = relu(aggs @ W0 + b0) -> LDS bf16 swizzled
    {
        int f = t & 127;
        int g0 = t >> 7;
        float wreg[N_FEAT];
#pragma unroll
        for (int k = 0; k < N_FEAT; k++) wreg[k] = Ws[k * HID + f];
#pragma unroll
        for (int j = 0; j < 32; j++) {
            int nl = g0 + j * 2;
            float acc = bs[f];
#pragma unroll
            for (int k = 0; k < N_FEAT; k++) acc += aggs[nl][k] * wreg[k];
            int boff = (nl * 256 + f * 2) ^ ((nl & 7) << 4);
            *(unsigned short*)((char*)hl + boff) = f2bf(fmaxf(acc, 0.f));
        }
    }
    __syncthreads();
    mfma_tail(hl, Wt1, dinv, u1, nb, n, t);
}

// ---- fused gather+GEMM2: gather(u1)+b1+relu -> h1 in LDS -> MFMA Wt2 -> u2 ----
// quarter-wave per node, 4 nodes per quarter (64 nodes/block), 8-deep pipeline
__global__ __launch_bounds__(256) void k_gfm(const unsigned int* __restrict__ ubf,
                                             const int* __restrict__ off,
                                             const int* __restrict__ indeg,
                                             const int* __restrict__ csr,
                                             const float* __restrict__ dinv,
                                             const float* __restrict__ bias,
                                             const unsigned short* __restrict__ Wt2,
                                             unsigned short* __restrict__ u2, int n) {
    __shared__ __align__(16) unsigned short hl[64 * 128];   // swizzled bf16
    int t = threadIdx.x;
    int Q = t >> 4;            // quarter-wave index 0..15
    int l4 = t & 15;
    int nb = blockIdx.x * 64;
    const uint4* U = (const uint4*)ubf;
    float4 bb0 = *(const float4*)&bias[l4 * 8];
    float4 bb1 = *(const float4*)&bias[l4 * 8 + 4];
#pragma unroll
    for (int i = 0; i < 4; i++) {
        int slot = Q * 4 + i;
        int d = nb + slot;
        if (d < n) {
            int s0 = off[d], c = indeg[d];
            float a[8] = {0.f, 0.f, 0.f, 0.f, 0.f, 0.f, 0.f, 0.f};
            addrow8(a, U[(size_t)d * 16 + l4]);   // self term
            int p = 0;
            for (; p + 7 < c; p += 8) {
                int s_[8];
#pragma unroll
                for (int j = 0; j < 8; j++) s_[j] = csr[s0 + p + j];
                uint4 v[8];
#pragma unroll
                for (int j = 0; j < 8; j++) v[j] = U[(size_t)s_[j] * 16 + l4];
#pragma unroll
                for (int j = 0; j < 8; j++) addrow8(a, v[j]);
            }
            if (p + 3 < c) {
                int s_[4];
#pragma unroll
                for (int j = 0; j < 4; j++) s_[j] = csr[s0 + p + j];
                uint4 v[4];
#pragma unroll
                for (int j = 0; j < 4; j++) v[j] = U[(size_t)s_[j] * 16 + l4];
#pragma unroll
                for (int j = 0; j < 4; j++) addrow8(a, v[j]);
                p += 4;
            }
            for (; p < c; p++) addrow8(a, U[(size_t)csr[s0 + p] * 16 + l4]);

            float dv = dinv[d];
            ushort8 hh;
            hh[0] = f2bf(fmaxf(dv * a[0] + bb0.x, 0.f));
            hh[1] = f2bf(fmaxf(dv * a[1] + bb0.y, 0.f));
            hh[2] = f2bf(fmaxf(dv * a[2] + bb0.z, 0.f));
            hh[3] = f2bf(fmaxf(dv * a[3] + bb0.w, 0.f));
            hh[4] = f2bf(fmaxf(dv * a[4] + bb1.x, 0.f));
            hh[5] = f2bf(fmaxf(dv * a[5] + bb1.y, 0.f));
            hh[6] = f2bf(fmaxf(dv * a[6] + bb1.z, 0.f));
            hh[7] = f2bf(fmaxf(dv * a[7] + bb1.w, 0.f));
            int boff = (slot * 256 + l4 * 16) ^ ((slot & 7) << 4);
            *(ushort8*)((char*)hl + boff) = hh;
        }
    }
    __syncthreads();
    mfma_tail(hl, Wt2, dinv, u2, nb, n, t);
}

// ---- layer-2 gather (quarter-wave, uint4) fused with mean-pool accumulation ----
__global__ void k_gather128p(const unsigned int* __restrict__ ubf, const int* __restrict__ off,
                             const int* __restrict__ indeg, const int* __restrict__ csr,
                             const float* __restrict__ dinv, const float* __restrict__ bias,
                             const int* __restrict__ batch, float* __restrict__ pooledm, int n) {
    __shared__ __align__(16) float part[16][128];
    __shared__ int bid[16];
    int t = threadIdx.x;
    int lane = t & 63;
    int quad = lane >> 4, l4 = lane & 15;
    int slot = (t >> 6) * 4 + quad;           // 0..15
    int d = blockIdx.x * 16 + slot;
    const uint4* U = (const uint4*)ubf;
    if (d < n) {
        int s0 = off[d], c = indeg[d];
        float a[8] = {0.f, 0.f, 0.f, 0.f, 0.f, 0.f, 0.f, 0.f};
        addrow8(a, U[(size_t)d * 16 + l4]);
        int p = 0;
        for (; p + 7 < c; p += 8) {
            int s_[8];
#pragma unroll
            for (int j = 0; j < 8; j++) s_[j] = csr[s0 + p + j];
            uint4 v[8];
#pragma unroll
            for (int j = 0; j < 8; j++) v[j] = U[(size_t)s_[j] * 16 + l4];
#pragma unroll
            for (int j = 0; j < 8; j++) addrow8(a, v[j]);
        }
        if (p + 3 < c) {
            int s_[4];
#pragma unroll
            for (int j = 0; j < 4; j++) s_[j] = csr[s0 + p + j];
            uint4 v[4];
#pragma unroll
            for (int j = 0; j < 4; j++) v[j] = U[(size_t)s_[j] * 16 + l4];
#pragma unroll
            for (int j = 0; j < 4; j++) addrow8(a, v[j]);
            p += 4;
        }
        for (; p < c; p++) addrow8(a, U[(size_t)csr[s0 + p] * 16 + l4]);

        float dv = dinv[d];
        float4 bb0 = *(const float4*)&bias[l4 * 8];
        float4 bb1 = *(const float4*)&bias[l4 * 8 + 4];
        float4 r0 = {dv * a[0] + bb0.x, dv * a[1] + bb0.y, dv * a[2] + bb0.z, dv * a[3] + bb0.w};
        float4 r1 = {dv * a[4] + bb1.x, dv * a[5] + bb1.y, dv * a[6] + bb1.z, dv * a[7] + bb1.w};
        *(float4*)&part[slot][l4 * 8] = r0;
        *(float4*)&part[slot][l4 * 8 + 4] = r1;
        if (l4 == 0) bid[slot] = batch[d];
    } else {
        if (l4 == 0) bid[slot] = -1;
    }
    __syncthreads();
    if (t < 128) {      // per-feature run reduction over the 16 nodes
        int f = t;
        float acc = 0.f;
        int g = -1;
        for (int j = 0; j < 16; j++) {
            int bj = bid[j];
            if (bj < 0) break;    // tail block: invalid nodes are trailing
            if (bj != g) {
                if (g >= 0) atomicAdd(&pooledm[g * HID + f], acc);
                g = bj; acc = 0.f;
            }
            acc += part[j][f];
        }
        if (g >= 0) atomicAdd(&pooledm[g * HID + f], acc);
    }
}

// -------------------- graph node counts --------------------
__global__ void k_cnt(const int* __restrict__ batch, int* __restrict__ cnt, int n) {
    int i = blockIdx.x * 256 + threadIdx.x;
    if (i < n) atomicAdd(&cnt[batch[i]], 1);
}

// -------------------- fused MLP head: fc0 + fc1 + fco --------------------
__global__ void k_head(const float* __restrict__ pooledm, const int* __restrict__ cnt,
                       const float* __restrict__ Wf0, const float* __restrict__ bf0,
                       const float* __restrict__ Wf1, const float* __restrict__ bf1,
                       const float* __restrict__ Wo, const float* __restrict__ bo,
                       float* __restrict__ out) {
    __shared__ float row[128];
    __shared__ float f0[256];
    __shared__ float f1[128];
    int g = blockIdx.x, t = threadIdx.x;   // 256 threads
    if (t < 128) row[t] = pooledm[g * 128 + t] * (1.f / (float)max(cnt[g], 1));
    __syncthreads();
    {
        float acc = 0.f;
#pragma unroll 8
        for (int k = 0; k < 128; k++) acc += row[k] * Wf0[k * 256 + t];
        f0[t] = fmaxf(acc + bf0[t], 0.f);
    }
    __syncthreads();
    if (t < 128) {
        float acc = 0.f;
#pragma unroll 8
        for (int k = 0; k < 256; k++) acc += f0[k] * Wf1[k * 128 + t];
        f1[t] = fmaxf(acc + bf1[t], 0.f);
    }
    __syncthreads();
    if (t < 64) {
        float acc = f1[t] * Wo[t] + f1[t + 64] * Wo[64 + t];
        for (int s = 32; s > 0; s >>= 1) acc += __shfl_down(acc, s);
        if (t == 0) out[g] = acc + bo[0];
    }
}

// -------------------- launch --------------------
extern "C" void kernel_launch(void* const* d_in, const int* in_sizes, int n_in,
                              void* d_out, int out_size, void* d_ws, size_t ws_size,
                              hipStream_t stream) {
    const float* x   = (const float*)d_in[0];
    const int* ei    = (const int*)d_in[1];
    const int* src   = ei;
    const int* dst   = ei + N_EDGES;
    const int* batch = (const int*)d_in[2];
    const float* W0 = (const float*)d_in[3];  const float* b0 = (const float*)d_in[4];
    const float* W1 = (const float*)d_in[5];  const float* b1 = (const float*)d_in[6];
    const float* W2 = (const float*)d_in[7];  const float* b2 = (const float*)d_in[8];
    const float* Wf0 = (const float*)d_in[9];  const float* bf0 = (const float*)d_in[10];
    const float* Wf1 = (const float*)d_in[11]; const float* bf1 = (const float*)d_in[12];
    const float* Wo = (const float*)d_in[13];  const float* bo = (const float*)d_in[14];
    float* out = (float*)d_out;

    char* w = (char*)d_ws;
    size_t o = 0;
    auto take = [&](size_t bytes) -> char* {
        char* p = w + o;
        o += (bytes + 255) & ~(size_t)255;
        return p;
    };
    int* indeg    = (int*)take((size_t)N_NODES * 4);
    int* off      = (int*)take((size_t)N_NODES * 4);
    int* counts   = (int*)take((size_t)N2 * 4);
    int* countsT  = (int*)take((size_t)N2 * 4);
    int* scT      = (int*)take((size_t)N2 * 4);
    int* bsum     = (int*)take(256 * 4);
    int* bpre     = (int*)take(256 * 4);
    int* csr      = (int*)take((size_t)N_EDGES * 4);
    float* dinv   = (float*)take((size_t)N_NODES * 4);
    int* cnt      = (int*)take((size_t)N_GRAPHS * 4);
    float* xs     = (float*)take((size_t)N_NODES * 16 * 4);
    unsigned short* ubfA = (unsigned short*)take((size_t)N_NODES * HID * 2);
    unsigned short* ubfB = (unsigned short*)take((size_t)N_NODES * HID * 2);
    unsigned short* Wt1  = (unsigned short*)take((size_t)HID * HID * 2);
    unsigned short* Wt2  = (unsigned short*)take((size_t)HID * HID * 2);
    float* pooledm= (float*)take((size_t)N_GRAPHS * HID * 4);
    // bstore (6.4MB) aliases ubfA (25.6MB): bstore dead after k_bfill; ubfA written later
    unsigned int* bstore = (unsigned int*)ubfA;

    hipMemsetAsync(cnt, 0, (size_t)N_GRAPHS * 4, stream);
    hipMemsetAsync(pooledm, 0, (size_t)N_GRAPHS * HID * 4, stream);

    // ---- topology: contention-free counting sort by dst bucket ----
    k_hist1<<<NBLK, 256, 0, stream>>>(dst, counts, N_EDGES);
    k_transp<<<(N2 + 255) / 256, 256, 0, stream>>>(counts, countsT);
    int nb2 = (N2 + 1023) / 1024;
    k_scan1<<<nb2, 256, 0, stream>>>(countsT, scT, bsum, N2);
    k_scan_block<<<1, 256, 0, stream>>>(bsum, bpre, nb2);
    k_scan3<<<(N2 + 255) / 256, 256, 0, stream>>>(scT, bpre, N2);
    k_scatter<<<NBLK, 256, 0, stream>>>(src, dst, scT, bstore, N_EDGES);
    k_bhistx<<<NB, 256, 0, stream>>>(bstore, scT, x, indeg, dinv, xs, N_NODES, N_EDGES);
    int nb1 = (N_NODES + 1023) / 1024;
    k_scan1<<<nb1, 256, 0, stream>>>(indeg, off, bsum, N_NODES);
    k_scan_block<<<1, 256, 0, stream>>>(bsum, bpre, nb1);
    k_scan3<<<(N_NODES + 255) / 256, 256, 0, stream>>>(off, bpre, N_NODES);
    k_bfill<<<NB, 256, 0, stream>>>(bstore, scT, off, csr, N_NODES, N_EDGES);
    k_cnt<<<(N_NODES + 255) / 256, 256, 0, stream>>>(batch, cnt, N_NODES);
    k_wcast2<<<(HID * HID + 255) / 256, 256, 0, stream>>>(W1, W2, Wt1, Wt2);

    // layer 0 + GEMM1 fused -> u1
    k_gf13m<<<(N_NODES + 63) / 64, 256, 0, stream>>>(xs, off, indeg, csr, dinv, W0, b0, Wt1, ubfA, N_NODES);
    // layer-1 gather + GEMM2 fused -> u2
    k_gfm<<<(N_NODES + 63) / 64, 256, 0, stream>>>((const unsigned int*)ubfA, off, indeg, csr, dinv, b1, Wt2, ubfB, N_NODES);
    // layer-2 gather fused with mean-pool accumulation
    k_gather128p<<<(N_NODES + 15) / 16, 256, 0, stream>>>((const unsigned int*)ubfB, off, indeg, csr, dinv, b2, batch, pooledm, N_NODES);

    // fused MLP head
    k_head<<<N_GRAPHS, 256, 0, stream>>>(pooledm, cnt, Wf0, bf0, Wf1, bf1, Wo, bo, out);
}

// Round 11
// 320.922 us; speedup vs baseline: 1.1142x; 1.1142x over previous
//
#include <hip/hip_runtime.h>
#include <hip/hip_bf16.h>

#define N_NODES  100000
#define N_EDGES  1600000
#define N_GRAPHS 2000
#define N_FEAT   13
#define HID      128
#define NB       ((N_NODES + 127) / 128)   // 782 buckets of 128 nodes
#define NBLK     256                        // edge-partition blocks for the sort
#define LOG_NBLK 8
#define N2       (NB * NBLK)                // 200192 (bucket,block) windows

typedef __attribute__((ext_vector_type(8))) short bf16x8;   // 8 bf16 = 4 VGPRs
typedef __attribute__((ext_vector_type(4))) float f32x4;
typedef __attribute__((ext_vector_type(8))) unsigned short ushort8;

// ============ contention-free counting sort of edges by dst bucket ============
__global__ void k_hist1(const int* __restrict__ dst, int* __restrict__ counts, int E) {
    __shared__ int hist[NB];
    int k = blockIdx.x, t = threadIdx.x;
    for (int b = t; b < NB; b += 256) hist[b] = 0;
    __syncthreads();
    int epb = (E + NBLK - 1) / NBLK;
    int base = k * epb, lim = min(base + epb, E);
    for (int i = base + t; i < lim; i += 256) atomicAdd(&hist[dst[i] >> 7], 1);
    __syncthreads();
    for (int b = t; b < NB; b += 256) counts[k * NB + b] = hist[b];
}

// scan over the TRANSPOSED counts (bucket-major), fused transpose-read:
// element i == counts[(i & (NBLK-1)) * NB + (i >> LOG_NBLK)]
__global__ void k_scan1T(const int* __restrict__ counts, int* __restrict__ out,
                         int* __restrict__ bsum, int n2) {
    __shared__ int ts[256];
    int t = threadIdx.x;
    int base = blockIdx.x * 1024 + t * 4;
    auto ld = [&](int i) -> int {
        return (i < n2) ? counts[(i & (NBLK - 1)) * NB + (i >> LOG_NBLK)] : 0;
    };
    int v0 = ld(base + 0), v1 = ld(base + 1), v2 = ld(base + 2), v3 = ld(base + 3);
    int s = v0 + v1 + v2 + v3;
    ts[t] = s;
    __syncthreads();
    for (int o = 1; o < 256; o <<= 1) {
        int x = (t >= o) ? ts[t - o] : 0;
        __syncthreads();
        ts[t] += x;
        __syncthreads();
    }
    if (t == 255) bsum[blockIdx.x] = ts[255];
    int run = ts[t] - s;
    if (base + 0 < n2) out[base + 0] = run; run += v0;
    if (base + 1 < n2) out[base + 1] = run; run += v1;
    if (base + 2 < n2) out[base + 2] = run; run += v2;
    if (base + 3 < n2) out[base + 3] = run;
}

__global__ void k_scan_block(const int* __restrict__ in, int* __restrict__ out, int len) {
    __shared__ int ts[256];
    int t = threadIdx.x;
    int v[8];
    int s = 0;
#pragma unroll
    for (int j = 0; j < 8; j++) {
        int i = t * 8 + j;
        v[j] = (i < len) ? in[i] : 0;
        s += v[j];
    }
    ts[t] = s;
    __syncthreads();
    for (int o = 1; o < 256; o <<= 1) {
        int x = (t >= o) ? ts[t - o] : 0;
        __syncthreads();
        ts[t] += x;
        __syncthreads();
    }
    int run = ts[t] - s;
#pragma unroll
    for (int j = 0; j < 8; j++) {
        int i = t * 8 + j;
        if (i < len) out[i] = run;
        run += v[j];
    }
}

__global__ void k_scan3(int* __restrict__ out, const int* __restrict__ bpre, int n) {
    int i = blockIdx.x * 256 + threadIdx.x;
    if (i < n) out[i] += bpre[i >> 10];
}

__global__ void k_scatter(const int* __restrict__ src, const int* __restrict__ dst,
                          const int* __restrict__ scT, unsigned int* __restrict__ bstore, int E) {
    __shared__ int cnt[NB];
    int k = blockIdx.x, t = threadIdx.x;
    for (int b = t; b < NB; b += 256) cnt[b] = 0;
    __syncthreads();
    int epb = (E + NBLK - 1) / NBLK;
    int base = k * epb, lim = min(base + epb, E);
    for (int i = base + t; i < lim; i += 256) {
        int d = dst[i];
        int b = d >> 7;
        int r = atomicAdd(&cnt[b], 1);    // LDS rank within (bucket, block) window
        bstore[scT[b * NBLK + k] + r] = ((unsigned int)src[i] << 7) | (unsigned int)(d & 127);
    }
}

// per-bucket node histogram -> indeg + dinv + xs; ALSO off via LDS scan + bucket base
__global__ void k_bhistx(const unsigned int* __restrict__ bstore, const int* __restrict__ scT,
                         const float* __restrict__ x, int* __restrict__ indeg,
                         float* __restrict__ dinv, float* __restrict__ xs,
                         int* __restrict__ off, int n, int E) {
    __shared__ int cnt[128];
    __shared__ int pre[128];
    int b = blockIdx.x, t = threadIdx.x;
    if (t < 128) cnt[t] = 0;
    __syncthreads();
    int start = scT[b * NBLK];
    int end = (b + 1 < NB) ? scT[(b + 1) * NBLK] : E;
    for (int i = start + t; i < end; i += 256) atomicAdd(&cnt[bstore[i] & 127], 1);
    __syncthreads();
    if (t < 128) pre[t] = cnt[t];
    __syncthreads();
    for (int o = 1; o < 128; o <<= 1) {       // Hillis-Steele inclusive scan
        int v = (t < 128 && t >= o) ? pre[t - o] : 0;
        __syncthreads();
        if (t < 128) pre[t] += v;
        __syncthreads();
    }
    int node = b * 128 + t;
    if (t < 128 && node < n) {
        int c = cnt[t];
        indeg[node] = c;
        off[node] = start + pre[t] - c;       // exclusive prefix + bucket base
        float dv = rsqrtf((float)(c + 1));    // +1 self loop
        dinv[node] = dv;
        float r[16];
#pragma unroll
        for (int k = 0; k < N_FEAT; k++) r[k] = dv * x[node * N_FEAT + k];
        r[13] = r[14] = r[15] = 0.f;
        float4* o4 = (float4*)&xs[(size_t)node * 16];
        o4[0] = float4{r[0], r[1], r[2], r[3]};
        o4[1] = float4{r[4], r[5], r[6], r[7]};
        o4[2] = float4{r[8], r[9], r[10], r[11]};
        o4[3] = float4{r[12], r[13], r[14], r[15]};
    }
}

__global__ void k_bfill(const unsigned int* __restrict__ bstore, const int* __restrict__ scT,
                        const int* __restrict__ off, int* __restrict__ csr, int n, int E) {
    __shared__ int cur[128];
    __shared__ int loff[128];
    int b = blockIdx.x, t = threadIdx.x;
    if (t < 128) {
        cur[t] = 0;
        int node = b * 128 + t;
        loff[t] = (node < n) ? off[node] : 0;
    }
    __syncthreads();
    int start = scT[b * NBLK];
    int end = (b + 1 < NB) ? scT[(b + 1) * NBLK] : E;
    for (int i = start + t; i < end; i += 256) {
        unsigned int e = bstore[i];
        int dl = e & 127;
        int p = loff[dl] + atomicAdd(&cur[dl], 1);
        csr[p] = (int)(e >> 7);
    }
}

// -------------------- fp32 -> bf16 RTNE --------------------
__device__ __forceinline__ unsigned short f2bf(float f) {
    unsigned int b = __float_as_uint(f);
    b += 0x7fffu + ((b >> 16) & 1u);
    return (unsigned short)(b >> 16);
}

__device__ __forceinline__ void addrow8(float (&a)[8], uint4 v) {
    a[0] += __uint_as_float(v.x << 16);
    a[1] += __uint_as_float(v.x & 0xffff0000u);
    a[2] += __uint_as_float(v.y << 16);
    a[3] += __uint_as_float(v.y & 0xffff0000u);
    a[4] += __uint_as_float(v.z << 16);
    a[5] += __uint_as_float(v.z & 0xffff0000u);
    a[6] += __uint_as_float(v.w << 16);
    a[7] += __uint_as_float(v.w & 0xffff0000u);
}

// ---- layer 0 fused: gather (float4 per 4 lanes, 16 nodes/wave, 8-deep) + GEMM K=13 ----
__global__ __launch_bounds__(256) void k_gf13(const float* __restrict__ xs,
                                              const int* __restrict__ off,
                                              const int* __restrict__ indeg,
                                              const int* __restrict__ csr,
                                              const float* __restrict__ dinv,
                                              const float* __restrict__ W,
                                              const float* __restrict__ b,
                                              unsigned short* __restrict__ h, int n) {
    __shared__ float Ws[N_FEAT * HID];
    __shared__ __align__(16) float aggs[64][16];
    __shared__ float bs[HID];
    int t = threadIdx.x;
    for (int i = t; i < N_FEAT * HID; i += 256) Ws[i] = W[i];
    if (t < HID) bs[t] = b[t];
    int lane = t & 63;
    int slot = (t >> 6) * 16 + (lane >> 2);   // node slot 0..63 within block
    int l2 = lane & 3;                        // float4 index within 16-wide row
    int nb = blockIdx.x * 64;
    int d = nb + slot;
    const float4* X4 = (const float4*)xs;
    if (d < n) {
        int s0 = off[d], c = indeg[d];
        float4 acc = X4[(size_t)d * 4 + l2];   // self term (already dinv[d]-scaled)
        int p = 0;
        for (; p + 7 < c; p += 8) {            // 8 independent chains in flight
            int s_[8];
#pragma unroll
            for (int j = 0; j < 8; j++) s_[j] = csr[s0 + p + j];
            float4 v[8];
#pragma unroll
            for (int j = 0; j < 8; j++) v[j] = X4[(size_t)s_[j] * 4 + l2];
#pragma unroll
            for (int j = 0; j < 8; j++) {
                acc.x += v[j].x; acc.y += v[j].y; acc.z += v[j].z; acc.w += v[j].w;
            }
        }
        for (; p < c; p++) {
            float4 v = X4[(size_t)csr[s0 + p] * 4 + l2];
            acc.x += v.x; acc.y += v.y; acc.z += v.z; acc.w += v.w;
        }
        float dv = dinv[d];
        float4 r = {dv * acc.x, dv * acc.y, dv * acc.z, dv * acc.w};
        *(float4*)&aggs[slot][l2 * 4] = r;
    }
    __syncthreads();
    // h0 = bf16(relu(aggs @ W0 + b0)); thread owns one feature column, 32 nodes
    int f = t & 127;
    int g0 = t >> 7;                 // 0 or 1
    float wreg[N_FEAT];
#pragma unroll
    for (int k = 0; k < N_FEAT; k++) wreg[k] = Ws[k * HID + f];
#pragma unroll
    for (int j = 0; j < 32; j++) {
        int nl = g0 + j * 2;
        int dd = nb + nl;
        if (dd < n) {
            float acc = bs[f];
#pragma unroll
            for (int k = 0; k < N_FEAT; k++) acc += aggs[nl][k] * wreg[k];
            h[(size_t)dd * HID + f] = f2bf(fmaxf(acc, 0.f));
        }
    }
}

// ---------- W1,W2 (fp32 [K][N] row-major) -> Wt (bf16 [N][K]) in one launch ----------
__global__ void k_wcast2(const float* __restrict__ W1, const float* __restrict__ W2,
                         unsigned short* __restrict__ Wt1, unsigned short* __restrict__ Wt2) {
    int i = blockIdx.x * 256 + threadIdx.x;
    if (i < HID * HID) {
        int c = i >> 7, k = i & 127;
        Wt1[i] = f2bf(W1[k * HID + c]);
        Wt2[i] = f2bf(W2[k * HID + c]);
    }
}

// ---------- MFMA GEMM: ubf = bf16( dinv * (X @ W) ), X bf16 [n][128], Wt bf16 [128][128] ----------
__global__ __launch_bounds__(256) void k_mfma128(const unsigned short* __restrict__ X,
                                                 const unsigned short* __restrict__ Wt,
                                                 const float* __restrict__ dinv,
                                                 unsigned short* __restrict__ ubf, int n) {
    int t = threadIdx.x;
    int wave = t >> 6, lane = t & 63;
    int lrow = lane & 15;          // A row within tile / D col within col-tile
    int lk8 = (lane >> 4) * 8;     // k-chunk base within 32-wide K step
    int tile0 = blockIdx.x * 16 + wave * 4;   // first of 4 node-tiles for this wave

    f32x4 acc[4][8];
#pragma unroll
    for (int nt = 0; nt < 4; nt++)
#pragma unroll
        for (int ct = 0; ct < 8; ct++) acc[nt][ct] = f32x4{0.f, 0.f, 0.f, 0.f};

#pragma unroll
    for (int s = 0; s < 4; s++) {               // K steps of 32
        bf16x8 bfr[8];
#pragma unroll
        for (int ct = 0; ct < 8; ct++) {        // B frags: Wt[col][s*32+lk8 ..+8]
            int col = ct * 16 + lrow;
            bfr[ct] = *(const bf16x8*)&Wt[col * HID + s * 32 + lk8];
        }
#pragma unroll
        for (int nt = 0; nt < 4; nt++) {
            int row = min((tile0 + nt) * 16 + lrow, n - 1);
            bf16x8 afr = *(const bf16x8*)&X[(size_t)row * HID + s * 32 + lk8];
#pragma unroll
            for (int ct = 0; ct < 8; ct++)
                acc[nt][ct] = __builtin_amdgcn_mfma_f32_16x16x32_bf16(afr, bfr[ct], acc[nt][ct], 0, 0, 0);
        }
    }

    // D layout: col = lane&15 (within col-tile), row = (lane>>4)*4 + r
#pragma unroll
    for (int nt = 0; nt < 4; nt++) {
        int rbase = (tile0 + nt) * 16 + (lane >> 4) * 4;
#pragma unroll
        for (int r = 0; r < 4; r++) {
            int row = rbase + r;
            if (row < n) {
                float dv = dinv[row];
#pragma unroll
                for (int ct = 0; ct < 8; ct++)
                    ubf[(size_t)row * HID + ct * 16 + lrow] = f2bf(dv * acc[nt][ct][r]);
            }
        }
    }
}

// ---- layer-1 gather over bf16 rows: quarter-wave per dst, uint4 lanes, 8-deep ----
__global__ void k_gather128(const unsigned int* __restrict__ ubf, const int* __restrict__ off,
                            const int* __restrict__ indeg, const int* __restrict__ csr,
                            const float* __restrict__ dinv, const float* __restrict__ bias,
                            unsigned short* __restrict__ yh, int n) {
    int t = threadIdx.x;
    int lane = t & 63;
    int quad = lane >> 4, l4 = lane & 15;
    int d = blockIdx.x * 16 + (t >> 6) * 4 + quad;   // 16 nodes per 256-thread block
    if (d >= n) return;
    int s0 = off[d], c = indeg[d];
    const uint4* U = (const uint4*)ubf;   // one row = 16 uint4 (128 bf16)

    uint4 sv = U[(size_t)d * 16 + l4];    // self term
    float a[8] = {0.f, 0.f, 0.f, 0.f, 0.f, 0.f, 0.f, 0.f};
    addrow8(a, sv);

    int p = 0;
    for (; p + 7 < c; p += 8) {           // 8 rows in flight per quarter-wave
        int s_[8];
#pragma unroll
        for (int j = 0; j < 8; j++) s_[j] = csr[s0 + p + j];
        uint4 v[8];
#pragma unroll
        for (int j = 0; j < 8; j++) v[j] = U[(size_t)s_[j] * 16 + l4];
#pragma unroll
        for (int j = 0; j < 8; j++) addrow8(a, v[j]);
    }
    if (p + 3 < c) {
        int s_[4];
#pragma unroll
        for (int j = 0; j < 4; j++) s_[j] = csr[s0 + p + j];
        uint4 v[4];
#pragma unroll
        for (int j = 0; j < 4; j++) v[j] = U[(size_t)s_[j] * 16 + l4];
#pragma unroll
        for (int j = 0; j < 4; j++) addrow8(a, v[j]);
        p += 4;
    }
    for (; p < c; p++) addrow8(a, U[(size_t)csr[s0 + p] * 16 + l4]);

    float dv = dinv[d];
    float4 bb0 = *(const float4*)&bias[l4 * 8];
    float4 bb1 = *(const float4*)&bias[l4 * 8 + 4];
    float r[8];
    r[0] = dv * a[0] + bb0.x; r[1] = dv * a[1] + bb0.y;
    r[2] = dv * a[2] + bb0.z; r[3] = dv * a[3] + bb0.w;
    r[4] = dv * a[4] + bb1.x; r[5] = dv * a[5] + bb1.y;
    r[6] = dv * a[6] + bb1.z; r[7] = dv * a[7] + bb1.w;
    ushort8 hh;
#pragma unroll
    for (int j = 0; j < 8; j++) hh[j] = f2bf(fmaxf(r[j], 0.f));
    *(ushort8*)&yh[(size_t)d * HID + l4 * 8] = hh;
}

// ---- layer-2 gather (quarter-wave, uint4) fused with mean-pool accumulation ----
__global__ void k_gather128p(const unsigned int* __restrict__ ubf, const int* __restrict__ off,
                             const int* __restrict__ indeg, const int* __restrict__ csr,
                             const float* __restrict__ dinv, const float* __restrict__ bias,
                             const int* __restrict__ batch, float* __restrict__ pooledm, int n) {
    __shared__ __align__(16) float part[16][132];   // +4 pad: kill bank conflicts
    __shared__ int bid[16];
    int t = threadIdx.x;
    int lane = t & 63;
    int quad = lane >> 4, l4 = lane & 15;
    int slot = (t >> 6) * 4 + quad;           // 0..15
    int d = blockIdx.x * 16 + slot;
    const uint4* U = (const uint4*)ubf;
    if (d < n) {
        int s0 = off[d], c = indeg[d];
        float a[8] = {0.f, 0.f, 0.f, 0.f, 0.f, 0.f, 0.f, 0.f};
        addrow8(a, U[(size_t)d * 16 + l4]);
        int p = 0;
        for (; p + 7 < c; p += 8) {
            int s_[8];
#pragma unroll
            for (int j = 0; j < 8; j++) s_[j] = csr[s0 + p + j];
            uint4 v[8];
#pragma unroll
            for (int j = 0; j < 8; j++) v[j] = U[(size_t)s_[j] * 16 + l4];
#pragma unroll
            for (int j = 0; j < 8; j++) addrow8(a, v[j]);
        }
        if (p + 3 < c) {
            int s_[4];
#pragma unroll
            for (int j = 0; j < 4; j++) s_[j] = csr[s0 + p + j];
            uint4 v[4];
#pragma unroll
            for (int j = 0; j < 4; j++) v[j] = U[(size_t)s_[j] * 16 + l4];
#pragma unroll
            for (int j = 0; j < 4; j++) addrow8(a, v[j]);
            p += 4;
        }
        for (; p < c; p++) addrow8(a, U[(size_t)csr[s0 + p] * 16 + l4]);

        float dv = dinv[d];
        float4 bb0 = *(const float4*)&bias[l4 * 8];
        float4 bb1 = *(const float4*)&bias[l4 * 8 + 4];
        float4 r0 = {dv * a[0] + bb0.x, dv * a[1] + bb0.y, dv * a[2] + bb0.z, dv * a[3] + bb0.w};
        float4 r1 = {dv * a[4] + bb1.x, dv * a[5] + bb1.y, dv * a[6] + bb1.z, dv * a[7] + bb1.w};
        *(float4*)&part[slot][l4 * 8] = r0;
        *(float4*)&part[slot][l4 * 8 + 4] = r1;
        if (l4 == 0) bid[slot] = batch[d];
    } else {
        if (l4 == 0) bid[slot] = -1;
    }
    __syncthreads();
    if (t < 128) {      // per-feature run reduction over the 16 nodes
        int f = t;
        float acc = 0.f;
        int g = -1;
        for (int j = 0; j < 16; j++) {
            int bj = bid[j];
            if (bj < 0) break;    // tail block: invalid nodes are trailing
            if (bj != g) {
                if (g >= 0) atomicAdd(&pooledm[g * HID + f], acc);
                g = bj; acc = 0.f;
            }
            acc += part[j][f];
        }
        if (g >= 0) atomicAdd(&pooledm[g * HID + f], acc);
    }
}

// -------------------- graph node counts --------------------
__global__ void k_cnt(const int* __restrict__ batch, int* __restrict__ cnt, int n) {
    int i = blockIdx.x * 256 + threadIdx.x;
    if (i < n) atomicAdd(&cnt[batch[i]], 1);
}

// -------------------- fused MLP head: fc0 + fc1 + fco --------------------
__global__ void k_head(const float* __restrict__ pooledm, const int* __restrict__ cnt,
                       const float* __restrict__ Wf0, const float* __restrict__ bf0,
                       const float* __restrict__ Wf1, const float* __restrict__ bf1,
                       const float* __restrict__ Wo, const float* __restrict__ bo,
                       float* __restrict__ out) {
    __shared__ float row[128];
    __shared__ float f0[256];
    __shared__ float f1[128];
    int g = blockIdx.x, t = threadIdx.x;   // 256 threads
    if (t < 128) row[t] = pooledm[g * 128 + t] * (1.f / (float)max(cnt[g], 1));
    __syncthreads();
    {
        float acc = 0.f;
#pragma unroll 8
        for (int k = 0; k < 128; k++) acc += row[k] * Wf0[k * 256 + t];
        f0[t] = fmaxf(acc + bf0[t], 0.f);
    }
    __syncthreads();
    if (t < 128) {
        float acc = 0.f;
#pragma unroll 8
        for (int k = 0; k < 256; k++) acc += f0[k] * Wf1[k * 128 + t];
        f1[t] = fmaxf(acc + bf1[t], 0.f);
    }
    __syncthreads();
    if (t < 64) {
        float acc = f1[t] * Wo[t] + f1[t + 64] * Wo[64 + t];
        for (int s = 32; s > 0; s >>= 1) acc += __shfl_down(acc, s);
        if (t == 0) out[g] = acc + bo[0];
    }
}

// -------------------- launch --------------------
extern "C" void kernel_launch(void* const* d_in, const int* in_sizes, int n_in,
                              void* d_out, int out_size, void* d_ws, size_t ws_size,
                              hipStream_t stream) {
    const float* x   = (const float*)d_in[0];
    const int* ei    = (const int*)d_in[1];
    const int* src   = ei;
    const int* dst   = ei + N_EDGES;
    const int* batch = (const int*)d_in[2];
    const float* W0 = (const float*)d_in[3];  const float* b0 = (const float*)d_in[4];
    const float* W1 = (const float*)d_in[5];  const float* b1 = (const float*)d_in[6];
    const float* W2 = (const float*)d_in[7];  const float* b2 = (const float*)d_in[8];
    const float* Wf0 = (const float*)d_in[9];  const float* bf0 = (const float*)d_in[10];
    const float* Wf1 = (const float*)d_in[11]; const float* bf1 = (const float*)d_in[12];
    const float* Wo = (const float*)d_in[13];  const float* bo = (const float*)d_in[14];
    float* out = (float*)d_out;

    char* w = (char*)d_ws;
    size_t o = 0;
    auto take = [&](size_t bytes) -> char* {
        char* p = w + o;
        o += (bytes + 255) & ~(size_t)255;
        return p;
    };
    int* indeg    = (int*)take((size_t)N_NODES * 4);
    int* off      = (int*)take((size_t)N_NODES * 4);
    int* counts   = (int*)take((size_t)N2 * 4);
    int* scT      = (int*)take((size_t)N2 * 4);
    int* bsum     = (int*)take(256 * 4);
    int* bpre     = (int*)take(256 * 4);
    int* csr      = (int*)take((size_t)N_EDGES * 4);
    float* dinv   = (float*)take((size_t)N_NODES * 4);
    int* cnt      = (int*)take((size_t)N_GRAPHS * 4);
    float* xs     = (float*)take((size_t)N_NODES * 16 * 4);
    unsigned short* hbf0 = (unsigned short*)take((size_t)N_NODES * HID * 2);
    unsigned short* hbf1 = (unsigned short*)take((size_t)N_NODES * HID * 2);
    unsigned short* ubf  = (unsigned short*)take((size_t)N_NODES * HID * 2);
    unsigned short* Wt1  = (unsigned short*)take((size_t)HID * HID * 2);
    unsigned short* Wt2  = (unsigned short*)take((size_t)HID * HID * 2);
    float* pooledm= (float*)take((size_t)N_GRAPHS * HID * 4);
    // bstore (6.4MB) aliases ubf (25.6MB): bstore dead after k_bfill; ubf written later
    unsigned int* bstore = (unsigned int*)ubf;

    hipMemsetAsync(cnt, 0, (size_t)N_GRAPHS * 4, stream);
    hipMemsetAsync(pooledm, 0, (size_t)N_GRAPHS * HID * 4, stream);

    // ---- topology: contention-free counting sort by dst bucket ----
    k_hist1<<<NBLK, 256, 0, stream>>>(dst, counts, N_EDGES);
    int nb2 = (N2 + 1023) / 1024;
    k_scan1T<<<nb2, 256, 0, stream>>>(counts, scT, bsum, N2);
    k_scan_block<<<1, 256, 0, stream>>>(bsum, bpre, nb2);
    k_scan3<<<(N2 + 255) / 256, 256, 0, stream>>>(scT, bpre, N2);
    k_scatter<<<NBLK, 256, 0, stream>>>(src, dst, scT, bstore, N_EDGES);
    k_bhistx<<<NB, 256, 0, stream>>>(bstore, scT, x, indeg, dinv, xs, off, N_NODES, N_EDGES);
    k_bfill<<<NB, 256, 0, stream>>>(bstore, scT, off, csr, N_NODES, N_EDGES);
    k_cnt<<<(N_NODES + 255) / 256, 256, 0, stream>>>(batch, cnt, N_NODES);
    k_wcast2<<<(HID * HID + 255) / 256, 256, 0, stream>>>(W1, W2, Wt1, Wt2);

    // layer 0: fused gather(13-wide) + GEMM -> bf16 h0
    k_gf13<<<(N_NODES + 63) / 64, 256, 0, stream>>>(xs, off, indeg, csr, dinv, W0, b0, hbf0, N_NODES);
    // layer 1: MFMA GEMM + gather (bf16 out)
    k_mfma128<<<(N_NODES + 255) / 256, 256, 0, stream>>>(hbf0, Wt1, dinv, ubf, N_NODES);
    k_gather128<<<(N_NODES + 15) / 16, 256, 0, stream>>>((const unsigned int*)ubf, off, indeg, csr, dinv, b1, hbf1, N_NODES);
    // layer 2: MFMA GEMM + gather fused with mean-pool accumulation
    k_mfma128<<<(N_NODES + 255) / 256, 256, 0, stream>>>(hbf1, Wt2, dinv, ubf, N_NODES);
    k_gather128p<<<(N_NODES + 15) / 16, 256, 0, stream>>>((const unsigned int*)ubf, off, indeg, csr, dinv, b2, batch, pooledm, N_NODES);

    // fused MLP head
    k_head<<<N_GRAPHS, 256, 0, stream>>>(pooledm, cnt, Wf0, bf0, Wf1, bf1, Wo, bo, out);
}

// Round 12
// 307.873 us; speedup vs baseline: 1.1614x; 1.0424x over previous
//
#include <hip/hip_runtime.h>
#include <hip/hip_bf16.h>

#define N_NODES  100000
#define N_EDGES  1600000
#define N_GRAPHS 2000
#define N_FEAT   13
#define HID      128
#define NB       ((N_NODES + 127) / 128)   // 782 buckets of 128 nodes
#define NBLK     256                        // edge-partition blocks for the sort
#define LOG_NBLK 8
#define N2       (NB * NBLK)                // 200192 (bucket,block) windows

typedef __attribute__((ext_vector_type(8))) short bf16x8;   // 8 bf16 = 4 VGPRs
typedef __attribute__((ext_vector_type(4))) float f32x4;
typedef __attribute__((ext_vector_type(8))) unsigned short ushort8;

// -------------------- fp32 -> bf16 RTNE --------------------
__device__ __forceinline__ unsigned short f2bf(float f) {
    unsigned int b = __float_as_uint(f);
    b += 0x7fffu + ((b >> 16) & 1u);
    return (unsigned short)(b >> 16);
}

// ============ contention-free counting sort of edges by dst bucket ============
// + folded: W1/W2 transpose-cast (1 elem/thread) and cnt zeroing
__global__ void k_hist1(const int* __restrict__ dst, int* __restrict__ counts,
                        const float* __restrict__ W1, const float* __restrict__ W2,
                        unsigned short* __restrict__ Wt1, unsigned short* __restrict__ Wt2,
                        int* __restrict__ cnt, int E) {
    __shared__ int hist[NB];
    int k = blockIdx.x, t = threadIdx.x;
    int gid = k * 256 + t;                 // 65536 threads total
    if (gid < N_GRAPHS) cnt[gid] = 0;
    if (gid < HID * HID) {                 // Wt[c][k] = bf16(W[k][c])
        int c = gid >> 7, kk = gid & 127;
        Wt1[gid] = f2bf(W1[kk * HID + c]);
        Wt2[gid] = f2bf(W2[kk * HID + c]);
    }
    for (int b = t; b < NB; b += 256) hist[b] = 0;
    __syncthreads();
    int epb = (E + NBLK - 1) / NBLK;
    int base = k * epb, lim = min(base + epb, E);
    for (int i = base + t; i < lim; i += 256) atomicAdd(&hist[dst[i] >> 7], 1);
    __syncthreads();
    for (int b = t; b < NB; b += 256) counts[k * NB + b] = hist[b];
}

// scan over the TRANSPOSED counts (bucket-major), fused transpose-read
__global__ void k_scan1T(const int* __restrict__ counts, int* __restrict__ out,
                         int* __restrict__ bsum, int n2) {
    __shared__ int ts[256];
    int t = threadIdx.x;
    int base = blockIdx.x * 1024 + t * 4;
    auto ld = [&](int i) -> int {
        return (i < n2) ? counts[(i & (NBLK - 1)) * NB + (i >> LOG_NBLK)] : 0;
    };
    int v0 = ld(base + 0), v1 = ld(base + 1), v2 = ld(base + 2), v3 = ld(base + 3);
    int s = v0 + v1 + v2 + v3;
    ts[t] = s;
    __syncthreads();
    for (int o = 1; o < 256; o <<= 1) {
        int x = (t >= o) ? ts[t - o] : 0;
        __syncthreads();
        ts[t] += x;
        __syncthreads();
    }
    if (t == 255) bsum[blockIdx.x] = ts[255];
    int run = ts[t] - s;
    if (base + 0 < n2) out[base + 0] = run; run += v0;
    if (base + 1 < n2) out[base + 1] = run; run += v1;
    if (base + 2 < n2) out[base + 2] = run; run += v2;
    if (base + 3 < n2) out[base + 3] = run;
}

__global__ void k_scan_block(const int* __restrict__ in, int* __restrict__ out, int len) {
    __shared__ int ts[256];
    int t = threadIdx.x;
    int v[8];
    int s = 0;
#pragma unroll
    for (int j = 0; j < 8; j++) {
        int i = t * 8 + j;
        v[j] = (i < len) ? in[i] : 0;
        s += v[j];
    }
    ts[t] = s;
    __syncthreads();
    for (int o = 1; o < 256; o <<= 1) {
        int x = (t >= o) ? ts[t - o] : 0;
        __syncthreads();
        ts[t] += x;
        __syncthreads();
    }
    int run = ts[t] - s;
#pragma unroll
    for (int j = 0; j < 8; j++) {
        int i = t * 8 + j;
        if (i < len) out[i] = run;
        run += v[j];
    }
}

__global__ void k_scan3(int* __restrict__ out, const int* __restrict__ bpre, int n) {
    int i = blockIdx.x * 256 + threadIdx.x;
    if (i < n) out[i] += bpre[i >> 10];
}

// + folded: pooledm zeroing (64000 float4 over 65536 threads)
__global__ void k_scatter(const int* __restrict__ src, const int* __restrict__ dst,
                          const int* __restrict__ scT, unsigned int* __restrict__ bstore,
                          float* __restrict__ pooledm, int E) {
    __shared__ int cnt[NB];
    int k = blockIdx.x, t = threadIdx.x;
    int gid = k * 256 + t;
    if (gid < (N_GRAPHS * HID) / 4)
        *(float4*)&pooledm[gid * 4] = float4{0.f, 0.f, 0.f, 0.f};
    for (int b = t; b < NB; b += 256) cnt[b] = 0;
    __syncthreads();
    int epb = (E + NBLK - 1) / NBLK;
    int base = k * epb, lim = min(base + epb, E);
    for (int i = base + t; i < lim; i += 256) {
        int d = dst[i];
        int b = d >> 7;
        int r = atomicAdd(&cnt[b], 1);    // LDS rank within (bucket, block) window
        bstore[scT[b * NBLK + k] + r] = ((unsigned int)src[i] << 7) | (unsigned int)(d & 127);
    }
}

// per-bucket: histogram -> indeg/off/dinv/xs, graph-count atomics, AND csr fill (fused bfill)
__global__ void k_bhistx(const unsigned int* __restrict__ bstore, const int* __restrict__ scT,
                         const float* __restrict__ x, const int* __restrict__ batch,
                         int* __restrict__ indeg, float* __restrict__ dinv,
                         float* __restrict__ xs, int* __restrict__ off,
                         int* __restrict__ cnt, int* __restrict__ csr, int n, int E) {
    __shared__ int hc[128];
    __shared__ int pre[128];
    __shared__ int loff[128];
    int b = blockIdx.x, t = threadIdx.x;
    if (t < 128) hc[t] = 0;
    __syncthreads();
    int start = scT[b * NBLK];
    int end = (b + 1 < NB) ? scT[(b + 1) * NBLK] : E;
    for (int i = start + t; i < end; i += 256) atomicAdd(&hc[bstore[i] & 127], 1);
    __syncthreads();
    if (t < 128) pre[t] = hc[t];
    __syncthreads();
    for (int o = 1; o < 128; o <<= 1) {       // Hillis-Steele inclusive scan
        int v = (t < 128 && t >= o) ? pre[t - o] : 0;
        __syncthreads();
        if (t < 128) pre[t] += v;
        __syncthreads();
    }
    int node = b * 128 + t;
    if (t < 128) {
        int c = hc[t];
        int ex = start + pre[t] - c;          // exclusive prefix + bucket base
        loff[t] = ex;
        if (node < n) {
            indeg[node] = c;
            off[node] = ex;
            float dv = rsqrtf((float)(c + 1));    // +1 self loop
            dinv[node] = dv;
            atomicAdd(&cnt[batch[node]], 1);      // graph node count
            float r[16];
#pragma unroll
            for (int k = 0; k < N_FEAT; k++) r[k] = dv * x[node * N_FEAT + k];
            r[13] = r[14] = r[15] = 0.f;
            float4* o4 = (float4*)&xs[(size_t)node * 16];
            o4[0] = float4{r[0], r[1], r[2], r[3]};
            o4[1] = float4{r[4], r[5], r[6], r[7]};
            o4[2] = float4{r[8], r[9], r[10], r[11]};
            o4[3] = float4{r[12], r[13], r[14], r[15]};
        }
    }
    if (t < 128) hc[t] = 0;                   // reuse as fill cursors
    __syncthreads();
    for (int i = start + t; i < end; i += 256) {   // csr fill (window L2-hot)
        unsigned int e = bstore[i];
        int dl = e & 127;
        int p = loff[dl] + atomicAdd(&hc[dl], 1);
        csr[p] = (int)(e >> 7);
    }
}

__device__ __forceinline__ void addrow8(float (&a)[8], uint4 v) {
    a[0] += __uint_as_float(v.x << 16);
    a[1] += __uint_as_float(v.x & 0xffff0000u);
    a[2] += __uint_as_float(v.y << 16);
    a[3] += __uint_as_float(v.y & 0xffff0000u);
    a[4] += __uint_as_float(v.z << 16);
    a[5] += __uint_as_float(v.z & 0xffff0000u);
    a[6] += __uint_as_float(v.w << 16);
    a[7] += __uint_as_float(v.w & 0xffff0000u);
}

// ---- layer 0 fused: gather (float4 per 4 lanes, 16 nodes/wave, 8-deep) + GEMM K=13 ----
__global__ __launch_bounds__(256) void k_gf13(const float* __restrict__ xs,
                                              const int* __restrict__ off,
                                              const int* __restrict__ indeg,
                                              const int* __restrict__ csr,
                                              const float* __restrict__ dinv,
                                              const float* __restrict__ W,
                                              const float* __restrict__ b,
                                              unsigned short* __restrict__ h, int n) {
    __shared__ float Ws[N_FEAT * HID];
    __shared__ __align__(16) float aggs[64][16];
    __shared__ float bs[HID];
    int t = threadIdx.x;
    for (int i = t; i < N_FEAT * HID; i += 256) Ws[i] = W[i];
    if (t < HID) bs[t] = b[t];
    int lane = t & 63;
    int slot = (t >> 6) * 16 + (lane >> 2);   // node slot 0..63 within block
    int l2 = lane & 3;                        // float4 index within 16-wide row
    int nb = blockIdx.x * 64;
    int d = nb + slot;
    const float4* X4 = (const float4*)xs;
    if (d < n) {
        int s0 = off[d], c = indeg[d];
        float4 acc = X4[(size_t)d * 4 + l2];   // self term (already dinv[d]-scaled)
        int p = 0;
        for (; p + 7 < c; p += 8) {            // 8 independent chains in flight
            int s_[8];
#pragma unroll
            for (int j = 0; j < 8; j++) s_[j] = csr[s0 + p + j];
            float4 v[8];
#pragma unroll
            for (int j = 0; j < 8; j++) v[j] = X4[(size_t)s_[j] * 4 + l2];
#pragma unroll
            for (int j = 0; j < 8; j++) {
                acc.x += v[j].x; acc.y += v[j].y; acc.z += v[j].z; acc.w += v[j].w;
            }
        }
        for (; p < c; p++) {
            float4 v = X4[(size_t)csr[s0 + p] * 4 + l2];
            acc.x += v.x; acc.y += v.y; acc.z += v.z; acc.w += v.w;
        }
        float dv = dinv[d];
        float4 r = {dv * acc.x, dv * acc.y, dv * acc.z, dv * acc.w};
        *(float4*)&aggs[slot][l2 * 4] = r;
    }
    __syncthreads();
    // h0 = bf16(relu(aggs @ W0 + b0)); thread owns one feature column, 32 nodes
    int f = t & 127;
    int g0 = t >> 7;                 // 0 or 1
    float wreg[N_FEAT];
#pragma unroll
    for (int k = 0; k < N_FEAT; k++) wreg[k] = Ws[k * HID + f];
#pragma unroll
    for (int j = 0; j < 32; j++) {
        int nl = g0 + j * 2;
        int dd = nb + nl;
        if (dd < n) {
            float acc = bs[f];
#pragma unroll
            for (int k = 0; k < N_FEAT; k++) acc += aggs[nl][k] * wreg[k];
            h[(size_t)dd * HID + f] = f2bf(fmaxf(acc, 0.f));
        }
    }
}

// ---------- MFMA GEMM: ubf = bf16( dinv * (X @ W) ), X bf16 [n][128], Wt bf16 [128][128] ----------
__global__ __launch_bounds__(256) void k_mfma128(const unsigned short* __restrict__ X,
                                                 const unsigned short* __restrict__ Wt,
                                                 const float* __restrict__ dinv,
                                                 unsigned short* __restrict__ ubf, int n) {
    int t = threadIdx.x;
    int wave = t >> 6, lane = t & 63;
    int lrow = lane & 15;          // A row within tile / D col within col-tile
    int lk8 = (lane >> 4) * 8;     // k-chunk base within 32-wide K step
    int tile0 = blockIdx.x * 16 + wave * 4;   // first of 4 node-tiles for this wave

    f32x4 acc[4][8];
#pragma unroll
    for (int nt = 0; nt < 4; nt++)
#pragma unroll
        for (int ct = 0; ct < 8; ct++) acc[nt][ct] = f32x4{0.f, 0.f, 0.f, 0.f};

#pragma unroll
    for (int s = 0; s < 4; s++) {               // K steps of 32
        bf16x8 bfr[8];
#pragma unroll
        for (int ct = 0; ct < 8; ct++) {        // B frags: Wt[col][s*32+lk8 ..+8]
            int col = ct * 16 + lrow;
            bfr[ct] = *(const bf16x8*)&Wt[col * HID + s * 32 + lk8];
        }
#pragma unroll
        for (int nt = 0; nt < 4; nt++) {
            int row = min((tile0 + nt) * 16 + lrow, n - 1);
            bf16x8 afr = *(const bf16x8*)&X[(size_t)row * HID + s * 32 + lk8];
#pragma unroll
            for (int ct = 0; ct < 8; ct++)
                acc[nt][ct] = __builtin_amdgcn_mfma_f32_16x16x32_bf16(afr, bfr[ct], acc[nt][ct], 0, 0, 0);
        }
    }

    // D layout: col = lane&15 (within col-tile), row = (lane>>4)*4 + r
#pragma unroll
    for (int nt = 0; nt < 4; nt++) {
        int rbase = (tile0 + nt) * 16 + (lane >> 4) * 4;
#pragma unroll
        for (int r = 0; r < 4; r++) {
            int row = rbase + r;
            if (row < n) {
                float dv = dinv[row];
#pragma unroll
                for (int ct = 0; ct < 8; ct++)
                    ubf[(size_t)row * HID + ct * 16 + lrow] = f2bf(dv * acc[nt][ct][r]);
            }
        }
    }
}

// ---- layer-1 gather over bf16 rows: quarter-wave per dst, uint4 lanes, 8-deep ----
__global__ void k_gather128(const unsigned int* __restrict__ ubf, const int* __restrict__ off,
                            const int* __restrict__ indeg, const int* __restrict__ csr,
                            const float* __restrict__ dinv, const float* __restrict__ bias,
                            unsigned short* __restrict__ yh, int n) {
    int t = threadIdx.x;
    int lane = t & 63;
    int quad = lane >> 4, l4 = lane & 15;
    int d = blockIdx.x * 16 + (t >> 6) * 4 + quad;   // 16 nodes per 256-thread block
    if (d >= n) return;
    int s0 = off[d], c = indeg[d];
    const uint4* U = (const uint4*)ubf;   // one row = 16 uint4 (128 bf16)

    uint4 sv = U[(size_t)d * 16 + l4];    // self term
    float a[8] = {0.f, 0.f, 0.f, 0.f, 0.f, 0.f, 0.f, 0.f};
    addrow8(a, sv);

    int p = 0;
    for (; p + 7 < c; p += 8) {           // 8 rows in flight per quarter-wave
        int s_[8];
#pragma unroll
        for (int j = 0; j < 8; j++) s_[j] = csr[s0 + p + j];
        uint4 v[8];
#pragma unroll
        for (int j = 0; j < 8; j++) v[j] = U[(size_t)s_[j] * 16 + l4];
#pragma unroll
        for (int j = 0; j < 8; j++) addrow8(a, v[j]);
    }
    if (p + 3 < c) {
        int s_[4];
#pragma unroll
        for (int j = 0; j < 4; j++) s_[j] = csr[s0 + p + j];
        uint4 v[4];
#pragma unroll
        for (int j = 0; j < 4; j++) v[j] = U[(size_t)s_[j] * 16 + l4];
#pragma unroll
        for (int j = 0; j < 4; j++) addrow8(a, v[j]);
        p += 4;
    }
    for (; p < c; p++) addrow8(a, U[(size_t)csr[s0 + p] * 16 + l4]);

    float dv = dinv[d];
    float4 bb0 = *(const float4*)&bias[l4 * 8];
    float4 bb1 = *(const float4*)&bias[l4 * 8 + 4];
    float r[8];
    r[0] = dv * a[0] + bb0.x; r[1] = dv * a[1] + bb0.y;
    r[2] = dv * a[2] + bb0.z; r[3] = dv * a[3] + bb0.w;
    r[4] = dv * a[4] + bb1.x; r[5] = dv * a[5] + bb1.y;
    r[6] = dv * a[6] + bb1.z; r[7] = dv * a[7] + bb1.w;
    ushort8 hh;
#pragma unroll
    for (int j = 0; j < 8; j++) hh[j] = f2bf(fmaxf(r[j], 0.f));
    *(ushort8*)&yh[(size_t)d * HID + l4 * 8] = hh;
}

// ---- layer-2 gather (quarter-wave, uint4) fused with mean-pool accumulation ----
__global__ void k_gather128p(const unsigned int* __restrict__ ubf, const int* __restrict__ off,
                             const int* __restrict__ indeg, const int* __restrict__ csr,
                             const float* __restrict__ dinv, const float* __restrict__ bias,
                             const int* __restrict__ batch, float* __restrict__ pooledm, int n) {
    __shared__ __align__(16) float part[16][132];   // +4 pad
    __shared__ int bid[16];
    int t = threadIdx.x;
    int lane = t & 63;
    int quad = lane >> 4, l4 = lane & 15;
    int slot = (t >> 6) * 4 + quad;           // 0..15
    int d = blockIdx.x * 16 + slot;
    const uint4* U = (const uint4*)ubf;
    if (d < n) {
        int s0 = off[d], c = indeg[d];
        float a[8] = {0.f, 0.f, 0.f, 0.f, 0.f, 0.f, 0.f, 0.f};
        addrow8(a, U[(size_t)d * 16 + l4]);
        int p = 0;
        for (; p + 7 < c; p += 8) {
            int s_[8];
#pragma unroll
            for (int j = 0; j < 8; j++) s_[j] = csr[s0 + p + j];
            uint4 v[8];
#pragma unroll
            for (int j = 0; j < 8; j++) v[j] = U[(size_t)s_[j] * 16 + l4];
#pragma unroll
            for (int j = 0; j < 8; j++) addrow8(a, v[j]);
        }
        if (p + 3 < c) {
            int s_[4];
#pragma unroll
            for (int j = 0; j < 4; j++) s_[j] = csr[s0 + p + j];
            uint4 v[4];
#pragma unroll
            for (int j = 0; j < 4; j++) v[j] = U[(size_t)s_[j] * 16 + l4];
#pragma unroll
            for (int j = 0; j < 4; j++) addrow8(a, v[j]);
            p += 4;
        }
        for (; p < c; p++) addrow8(a, U[(size_t)csr[s0 + p] * 16 + l4]);

        float dv = dinv[d];
        float4 bb0 = *(const float4*)&bias[l4 * 8];
        float4 bb1 = *(const float4*)&bias[l4 * 8 + 4];
        float4 r0 = {dv * a[0] + bb0.x, dv * a[1] + bb0.y, dv * a[2] + bb0.z, dv * a[3] + bb0.w};
        float4 r1 = {dv * a[4] + bb1.x, dv * a[5] + bb1.y, dv * a[6] + bb1.z, dv * a[7] + bb1.w};
        *(float4*)&part[slot][l4 * 8] = r0;
        *(float4*)&part[slot][l4 * 8 + 4] = r1;
        if (l4 == 0) bid[slot] = batch[d];
    } else {
        if (l4 == 0) bid[slot] = -1;
    }
    __syncthreads();
    if (t < 128) {      // per-feature run reduction over the 16 nodes
        int f = t;
        float acc = 0.f;
        int g = -1;
        for (int j = 0; j < 16; j++) {
            int bj = bid[j];
            if (bj < 0) break;    // tail block: invalid nodes are trailing
            if (bj != g) {
                if (g >= 0) atomicAdd(&pooledm[g * HID + f], acc);
                g = bj; acc = 0.f;
            }
            acc += part[j][f];
        }
        if (g >= 0) atomicAdd(&pooledm[g * HID + f], acc);
    }
}

// -------------------- fused MLP head: fc0 + fc1 + fco --------------------
__global__ void k_head(const float* __restrict__ pooledm, const int* __restrict__ cnt,
                       const float* __restrict__ Wf0, const float* __restrict__ bf0,
                       const float* __restrict__ Wf1, const float* __restrict__ bf1,
                       const float* __restrict__ Wo, const float* __restrict__ bo,
                       float* __restrict__ out) {
    __shared__ float row[128];
    __shared__ float f0[256];
    __shared__ float f1[128];
    int g = blockIdx.x, t = threadIdx.x;   // 256 threads
    if (t < 128) row[t] = pooledm[g * 128 + t] * (1.f / (float)max(cnt[g], 1));
    __syncthreads();
    {
        float acc = 0.f;
#pragma unroll 8
        for (int k = 0; k < 128; k++) acc += row[k] * Wf0[k * 256 + t];
        f0[t] = fmaxf(acc + bf0[t], 0.f);
    }
    __syncthreads();
    if (t < 128) {
        float acc = 0.f;
#pragma unroll 8
        for (int k = 0; k < 256; k++) acc += f0[k] * Wf1[k * 128 + t];
        f1[t] = fmaxf(acc + bf1[t], 0.f);
    }
    __syncthreads();
    if (t < 64) {
        float acc = f1[t] * Wo[t] + f1[t + 64] * Wo[64 + t];
        for (int s = 32; s > 0; s >>= 1) acc += __shfl_down(acc, s);
        if (t == 0) out[g] = acc + bo[0];
    }
}

// -------------------- launch --------------------
extern "C" void kernel_launch(void* const* d_in, const int* in_sizes, int n_in,
                              void* d_out, int out_size, void* d_ws, size_t ws_size,
                              hipStream_t stream) {
    const float* x   = (const float*)d_in[0];
    const int* ei    = (const int*)d_in[1];
    const int* src   = ei;
    const int* dst   = ei + N_EDGES;
    const int* batch = (const int*)d_in[2];
    const float* W0 = (const float*)d_in[3];  const float* b0 = (const float*)d_in[4];
    const float* W1 = (const float*)d_in[5];  const float* b1 = (const float*)d_in[6];
    const float* W2 = (const float*)d_in[7];  const float* b2 = (const float*)d_in[8];
    const float* Wf0 = (const float*)d_in[9];  const float* bf0 = (const float*)d_in[10];
    const float* Wf1 = (const float*)d_in[11]; const float* bf1 = (const float*)d_in[12];
    const float* Wo = (const float*)d_in[13];  const float* bo = (const float*)d_in[14];
    float* out = (float*)d_out;

    char* w = (char*)d_ws;
    size_t o = 0;
    auto take = [&](size_t bytes) -> char* {
        char* p = w + o;
        o += (bytes + 255) & ~(size_t)255;
        return p;
    };
    int* indeg    = (int*)take((size_t)N_NODES * 4);
    int* off      = (int*)take((size_t)N_NODES * 4);
    int* counts   = (int*)take((size_t)N2 * 4);
    int* scT      = (int*)take((size_t)N2 * 4);
    int* bsum     = (int*)take(256 * 4);
    int* bpre     = (int*)take(256 * 4);
    int* csr      = (int*)take((size_t)N_EDGES * 4);
    float* dinv   = (float*)take((size_t)N_NODES * 4);
    int* cnt      = (int*)take((size_t)N_GRAPHS * 4);
    float* xs     = (float*)take((size_t)N_NODES * 16 * 4);
    unsigned short* hbf0 = (unsigned short*)take((size_t)N_NODES * HID * 2);
    unsigned short* hbf1 = (unsigned short*)take((size_t)N_NODES * HID * 2);
    unsigned short* ubf  = (unsigned short*)take((size_t)N_NODES * HID * 2);
    unsigned short* Wt1  = (unsigned short*)take((size_t)HID * HID * 2);
    unsigned short* Wt2  = (unsigned short*)take((size_t)HID * HID * 2);
    float* pooledm= (float*)take((size_t)N_GRAPHS * HID * 4);
    // bstore (6.4MB) aliases ubf (25.6MB): bstore dead after k_bhistx; ubf written later
    unsigned int* bstore = (unsigned int*)ubf;

    // ---- topology: contention-free counting sort by dst bucket ----
    k_hist1<<<NBLK, 256, 0, stream>>>(dst, counts, W1, W2, Wt1, Wt2, cnt, N_EDGES);
    int nb2 = (N2 + 1023) / 1024;
    k_scan1T<<<nb2, 256, 0, stream>>>(counts, scT, bsum, N2);
    k_scan_block<<<1, 256, 0, stream>>>(bsum, bpre, nb2);
    k_scan3<<<(N2 + 255) / 256, 256, 0, stream>>>(scT, bpre, N2);
    k_scatter<<<NBLK, 256, 0, stream>>>(src, dst, scT, bstore, pooledm, N_EDGES);
    // fused: histogram + off/dinv/xs + graph counts + csr fill
    k_bhistx<<<NB, 256, 0, stream>>>(bstore, scT, x, batch, indeg, dinv, xs, off, cnt, csr, N_NODES, N_EDGES);

    // layer 0: fused gather(13-wide) + GEMM -> bf16 h0
    k_gf13<<<(N_NODES + 63) / 64, 256, 0, stream>>>(xs, off, indeg, csr, dinv, W0, b0, hbf0, N_NODES);
    // layer 1: MFMA GEMM + gather (bf16 out)
    k_mfma128<<<(N_NODES + 255) / 256, 256, 0, stream>>>(hbf0, Wt1, dinv, ubf, N_NODES);
    k_gather128<<<(N_NODES + 15) / 16, 256, 0, stream>>>((const unsigned int*)ubf, off, indeg, csr, dinv, b1, hbf1, N_NODES);
    // layer 2: MFMA GEMM + gather fused with mean-pool accumulation
    k_mfma128<<<(N_NODES + 255) / 256, 256, 0, stream>>>(hbf1, Wt2, dinv, ubf, N_NODES);
    k_gather128p<<<(N_NODES + 15) / 16, 256, 0, stream>>>((const unsigned int*)ubf, off, indeg, csr, dinv, b2, batch, pooledm, N_NODES);

    // fused MLP head
    k_head<<<N_GRAPHS, 256, 0, stream>>>(pooledm, cnt, Wf0, bf0, Wf1, bf1, Wo, bo, out);
}

// Round 13
// 301.010 us; speedup vs baseline: 1.1879x; 1.0228x over previous
//
#include <hip/hip_runtime.h>
#include <hip/hip_bf16.h>

#define N_NODES  100000
#define N_EDGES  1600000
#define N_GRAPHS 2000
#define N_FEAT   13
#define HID      128
#define NB       ((N_NODES + 127) / 128)   // 782 buckets of 128 nodes
#define NBLK     256                        // edge-partition blocks for the sort
#define LOG_NBLK 8
#define N2       (NB * NBLK)                // 200192 (bucket,block) windows
#define EPB      (((N_EDGES + NBLK - 1) / NBLK + 3) & ~3)   // 6252: 4-aligned edges/block

typedef __attribute__((ext_vector_type(8))) short bf16x8;   // 8 bf16 = 4 VGPRs
typedef __attribute__((ext_vector_type(4))) float f32x4;
typedef __attribute__((ext_vector_type(8))) unsigned short ushort8;

// -------------------- fp32 -> bf16 RTNE --------------------
__device__ __forceinline__ unsigned short f2bf(float f) {
    unsigned int b = __float_as_uint(f);
    b += 0x7fffu + ((b >> 16) & 1u);
    return (unsigned short)(b >> 16);
}

// ============ contention-free counting sort of edges by dst bucket ============
// + folded: W1/W2 transpose-cast (1 elem/thread) and cnt zeroing; int4 edge loads
__global__ void k_hist1(const int* __restrict__ dst, int* __restrict__ counts,
                        const float* __restrict__ W1, const float* __restrict__ W2,
                        unsigned short* __restrict__ Wt1, unsigned short* __restrict__ Wt2,
                        int* __restrict__ cnt, int E) {
    __shared__ int hist[NB];
    int k = blockIdx.x, t = threadIdx.x;
    int gid = k * 256 + t;                 // 65536 threads total
    if (gid < N_GRAPHS) cnt[gid] = 0;
    if (gid < HID * HID) {                 // Wt[c][k] = bf16(W[k][c])
        int c = gid >> 7, kk = gid & 127;
        Wt1[gid] = f2bf(W1[kk * HID + c]);
        Wt2[gid] = f2bf(W2[kk * HID + c]);
    }
    for (int b = t; b < NB; b += 256) hist[b] = 0;
    __syncthreads();
    int base = k * EPB, lim = min(base + EPB, E);
    // every block's [base,lim) is 16B-aligned and a multiple of 4 edges
    for (int i = base + t * 4; i < lim; i += 1024) {
        int4 d4 = *(const int4*)&dst[i];
        atomicAdd(&hist[d4.x >> 7], 1);
        atomicAdd(&hist[d4.y >> 7], 1);
        atomicAdd(&hist[d4.z >> 7], 1);
        atomicAdd(&hist[d4.w >> 7], 1);
    }
    __syncthreads();
    for (int b = t; b < NB; b += 256) counts[k * NB + b] = hist[b];
}

// scan over the TRANSPOSED counts (bucket-major), fused transpose-read
__global__ void k_scan1T(const int* __restrict__ counts, int* __restrict__ out,
                         int* __restrict__ bsum, int n2) {
    __shared__ int ts[256];
    int t = threadIdx.x;
    int base = blockIdx.x * 1024 + t * 4;
    auto ld = [&](int i) -> int {
        return (i < n2) ? counts[(i & (NBLK - 1)) * NB + (i >> LOG_NBLK)] : 0;
    };
    int v0 = ld(base + 0), v1 = ld(base + 1), v2 = ld(base + 2), v3 = ld(base + 3);
    int s = v0 + v1 + v2 + v3;
    ts[t] = s;
    __syncthreads();
    for (int o = 1; o < 256; o <<= 1) {
        int x = (t >= o) ? ts[t - o] : 0;
        __syncthreads();
        ts[t] += x;
        __syncthreads();
    }
    if (t == 255) bsum[blockIdx.x] = ts[255];
    int run = ts[t] - s;
    if (base + 0 < n2) out[base + 0] = run; run += v0;
    if (base + 1 < n2) out[base + 1] = run; run += v1;
    if (base + 2 < n2) out[base + 2] = run; run += v2;
    if (base + 3 < n2) out[base + 3] = run;
}

__global__ void k_scan_block(const int* __restrict__ in, int* __restrict__ out, int len) {
    __shared__ int ts[256];
    int t = threadIdx.x;
    int v[8];
    int s = 0;
#pragma unroll
    for (int j = 0; j < 8; j++) {
        int i = t * 8 + j;
        v[j] = (i < len) ? in[i] : 0;
        s += v[j];
    }
    ts[t] = s;
    __syncthreads();
    for (int o = 1; o < 256; o <<= 1) {
        int x = (t >= o) ? ts[t - o] : 0;
        __syncthreads();
        ts[t] += x;
        __syncthreads();
    }
    int run = ts[t] - s;
#pragma unroll
    for (int j = 0; j < 8; j++) {
        int i = t * 8 + j;
        if (i < len) out[i] = run;
        run += v[j];
    }
}

// + folded: pooledm zeroing; int4 edge loads; scT+bpre fused (k_scan3 eliminated)
__global__ void k_scatter(const int* __restrict__ src, const int* __restrict__ dst,
                          const int* __restrict__ scT, const int* __restrict__ bpre,
                          unsigned int* __restrict__ bstore,
                          float* __restrict__ pooledm, int E) {
    __shared__ int cnt[NB];
    int k = blockIdx.x, t = threadIdx.x;
    int gid = k * 256 + t;
    if (gid < (N_GRAPHS * HID) / 4)
        *(float4*)&pooledm[gid * 4] = float4{0.f, 0.f, 0.f, 0.f};
    for (int b = t; b < NB; b += 256) cnt[b] = 0;
    __syncthreads();
    int base = k * EPB, lim = min(base + EPB, E);
    for (int i = base + t * 4; i < lim; i += 1024) {
        int4 s4 = *(const int4*)&src[i];
        int4 d4 = *(const int4*)&dst[i];
#pragma unroll
        for (int j = 0; j < 4; j++) {
            int d = (j == 0) ? d4.x : (j == 1) ? d4.y : (j == 2) ? d4.z : d4.w;
            int sv = (j == 0) ? s4.x : (j == 1) ? s4.y : (j == 2) ? s4.z : s4.w;
            int b = d >> 7;
            int idx = b * NBLK + k;
            int r = atomicAdd(&cnt[b], 1);    // LDS rank within (bucket, block) window
            bstore[scT[idx] + bpre[idx >> 10] + r] =
                ((unsigned int)sv << 7) | (unsigned int)(d & 127);
        }
    }
}

// per-bucket: histogram -> indeg/off/dinv/xs, graph-count atomics, AND csr fill
__global__ void k_bhistx(const unsigned int* __restrict__ bstore, const int* __restrict__ scT,
                         const int* __restrict__ bpre,
                         const float* __restrict__ x, const int* __restrict__ batch,
                         int* __restrict__ indeg, float* __restrict__ dinv,
                         float* __restrict__ xs, int* __restrict__ off,
                         int* __restrict__ cnt, int* __restrict__ csr, int n, int E) {
    __shared__ int hc[128];
    __shared__ int pre[128];
    __shared__ int loff[128];
    int b = blockIdx.x, t = threadIdx.x;
    if (t < 128) hc[t] = 0;
    __syncthreads();
    int i0 = b * NBLK;
    int start = scT[i0] + bpre[i0 >> 10];
    int end;
    if (b + 1 < NB) {
        int i1 = (b + 1) * NBLK;
        end = scT[i1] + bpre[i1 >> 10];
    } else {
        end = E;
    }
    for (int i = start + t; i < end; i += 256) atomicAdd(&hc[bstore[i] & 127], 1);
    __syncthreads();
    if (t < 128) pre[t] = hc[t];
    __syncthreads();
    for (int o = 1; o < 128; o <<= 1) {       // Hillis-Steele inclusive scan
        int v = (t < 128 && t >= o) ? pre[t - o] : 0;
        __syncthreads();
        if (t < 128) pre[t] += v;
        __syncthreads();
    }
    int node = b * 128 + t;
    if (t < 128) {
        int c = hc[t];
        int ex = start + pre[t] - c;          // exclusive prefix + bucket base
        loff[t] = ex;
        if (node < n) {
            indeg[node] = c;
            off[node] = ex;
            float dv = rsqrtf((float)(c + 1));    // +1 self loop
            dinv[node] = dv;
            atomicAdd(&cnt[batch[node]], 1);      // graph node count
            float r[16];
#pragma unroll
            for (int k = 0; k < N_FEAT; k++) r[k] = dv * x[node * N_FEAT + k];
            r[13] = r[14] = r[15] = 0.f;
            float4* o4 = (float4*)&xs[(size_t)node * 16];
            o4[0] = float4{r[0], r[1], r[2], r[3]};
            o4[1] = float4{r[4], r[5], r[6], r[7]};
            o4[2] = float4{r[8], r[9], r[10], r[11]};
            o4[3] = float4{r[12], r[13], r[14], r[15]};
        }
    }
    if (t < 128) hc[t] = 0;                   // reuse as fill cursors
    __syncthreads();
    for (int i = start + t; i < end; i += 256) {   // csr fill (window L2-hot)
        unsigned int e = bstore[i];
        int dl = e & 127;
        int p = loff[dl] + atomicAdd(&hc[dl], 1);
        csr[p] = (int)(e >> 7);
    }
}

__device__ __forceinline__ void addrow8(float (&a)[8], uint4 v) {
    a[0] += __uint_as_float(v.x << 16);
    a[1] += __uint_as_float(v.x & 0xffff0000u);
    a[2] += __uint_as_float(v.y << 16);
    a[3] += __uint_as_float(v.y & 0xffff0000u);
    a[4] += __uint_as_float(v.z << 16);
    a[5] += __uint_as_float(v.z & 0xffff0000u);
    a[6] += __uint_as_float(v.w << 16);
    a[7] += __uint_as_float(v.w & 0xffff0000u);
}

// ---- layer 0 fused: gather (float4 per 4 lanes, 16 nodes/wave, 8-deep) + GEMM K=13 ----
__global__ __launch_bounds__(256) void k_gf13(const float* __restrict__ xs,
                                              const int* __restrict__ off,
                                              const int* __restrict__ indeg,
                                              const int* __restrict__ csr,
                                              const float* __restrict__ dinv,
                                              const float* __restrict__ W,
                                              const float* __restrict__ b,
                                              unsigned short* __restrict__ h, int n) {
    __shared__ float Ws[N_FEAT * HID];
    __shared__ __align__(16) float aggs[64][16];
    __shared__ float bs[HID];
    int t = threadIdx.x;
    for (int i = t; i < N_FEAT * HID; i += 256) Ws[i] = W[i];
    if (t < HID) bs[t] = b[t];
    int lane = t & 63;
    int slot = (t >> 6) * 16 + (lane >> 2);   // node slot 0..63 within block
    int l2 = lane & 3;                        // float4 index within 16-wide row
    int nb = blockIdx.x * 64;
    int d = nb + slot;
    const float4* X4 = (const float4*)xs;
    if (d < n) {
        int s0 = off[d], c = indeg[d];
        float4 acc = X4[(size_t)d * 4 + l2];   // self term (already dinv[d]-scaled)
        int p = 0;
        for (; p + 7 < c; p += 8) {            // 8 independent chains in flight
            int s_[8];
#pragma unroll
            for (int j = 0; j < 8; j++) s_[j] = csr[s0 + p + j];
            float4 v[8];
#pragma unroll
            for (int j = 0; j < 8; j++) v[j] = X4[(size_t)s_[j] * 4 + l2];
#pragma unroll
            for (int j = 0; j < 8; j++) {
                acc.x += v[j].x; acc.y += v[j].y; acc.z += v[j].z; acc.w += v[j].w;
            }
        }
        for (; p < c; p++) {
            float4 v = X4[(size_t)csr[s0 + p] * 4 + l2];
            acc.x += v.x; acc.y += v.y; acc.z += v.z; acc.w += v.w;
        }
        float dv = dinv[d];
        float4 r = {dv * acc.x, dv * acc.y, dv * acc.z, dv * acc.w};
        *(float4*)&aggs[slot][l2 * 4] = r;
    }
    __syncthreads();
    // h0 = bf16(relu(aggs @ W0 + b0)); thread owns one feature column, 32 nodes
    int f = t & 127;
    int g0 = t >> 7;                 // 0 or 1
    float wreg[N_FEAT];
#pragma unroll
    for (int k = 0; k < N_FEAT; k++) wreg[k] = Ws[k * HID + f];
#pragma unroll
    for (int j = 0; j < 32; j++) {
        int nl = g0 + j * 2;
        int dd = nb + nl;
        if (dd < n) {
            float acc = bs[f];
#pragma unroll
            for (int k = 0; k < N_FEAT; k++) acc += aggs[nl][k] * wreg[k];
            h[(size_t)dd * HID + f] = f2bf(fmaxf(acc, 0.f));
        }
    }
}

// ---------- MFMA GEMM: ubf = bf16( dinv * (X @ W) ), X bf16 [n][128], Wt bf16 [128][128] ----------
__global__ __launch_bounds__(256) void k_mfma128(const unsigned short* __restrict__ X,
                                                 const unsigned short* __restrict__ Wt,
                                                 const float* __restrict__ dinv,
                                                 unsigned short* __restrict__ ubf, int n) {
    int t = threadIdx.x;
    int wave = t >> 6, lane = t & 63;
    int lrow = lane & 15;          // A row within tile / D col within col-tile
    int lk8 = (lane >> 4) * 8;     // k-chunk base within 32-wide K step
    int tile0 = blockIdx.x * 16 + wave * 4;   // first of 4 node-tiles for this wave

    f32x4 acc[4][8];
#pragma unroll
    for (int nt = 0; nt < 4; nt++)
#pragma unroll
        for (int ct = 0; ct < 8; ct++) acc[nt][ct] = f32x4{0.f, 0.f, 0.f, 0.f};

#pragma unroll
    for (int s = 0; s < 4; s++) {               // K steps of 32
        bf16x8 bfr[8];
#pragma unroll
        for (int ct = 0; ct < 8; ct++) {        // B frags: Wt[col][s*32+lk8 ..+8]
            int col = ct * 16 + lrow;
            bfr[ct] = *(const bf16x8*)&Wt[col * HID + s * 32 + lk8];
        }
#pragma unroll
        for (int nt = 0; nt < 4; nt++) {
            int row = min((tile0 + nt) * 16 + lrow, n - 1);
            bf16x8 afr = *(const bf16x8*)&X[(size_t)row * HID + s * 32 + lk8];
#pragma unroll
            for (int ct = 0; ct < 8; ct++)
                acc[nt][ct] = __builtin_amdgcn_mfma_f32_16x16x32_bf16(afr, bfr[ct], acc[nt][ct], 0, 0, 0);
        }
    }

    // D layout: col = lane&15 (within col-tile), row = (lane>>4)*4 + r
#pragma unroll
    for (int nt = 0; nt < 4; nt++) {
        int rbase = (tile0 + nt) * 16 + (lane >> 4) * 4;
#pragma unroll
        for (int r = 0; r < 4; r++) {
            int row = rbase + r;
            if (row < n) {
                float dv = dinv[row];
#pragma unroll
                for (int ct = 0; ct < 8; ct++)
                    ubf[(size_t)row * HID + ct * 16 + lrow] = f2bf(dv * acc[nt][ct][r]);
            }
        }
    }
}

// ---- layer-1 gather over bf16 rows: quarter-wave per dst, uint4 lanes, 8-deep ----
__global__ void k_gather128(const unsigned int* __restrict__ ubf, const int* __restrict__ off,
                            const int* __restrict__ indeg, const int* __restrict__ csr,
                            const float* __restrict__ dinv, const float* __restrict__ bias,
                            unsigned short* __restrict__ yh, int n) {
    int t = threadIdx.x;
    int lane = t & 63;
    int quad = lane >> 4, l4 = lane & 15;
    int d = blockIdx.x * 16 + (t >> 6) * 4 + quad;   // 16 nodes per 256-thread block
    if (d >= n) return;
    int s0 = off[d], c = indeg[d];
    const uint4* U = (const uint4*)ubf;   // one row = 16 uint4 (128 bf16)

    uint4 sv = U[(size_t)d * 16 + l4];    // self term
    float a[8] = {0.f, 0.f, 0.f, 0.f, 0.f, 0.f, 0.f, 0.f};
    addrow8(a, sv);

    int p = 0;
    for (; p + 7 < c; p += 8) {           // 8 rows in flight per quarter-wave
        int s_[8];
#pragma unroll
        for (int j = 0; j < 8; j++) s_[j] = csr[s0 + p + j];
        uint4 v[8];
#pragma unroll
        for (int j = 0; j < 8; j++) v[j] = U[(size_t)s_[j] * 16 + l4];
#pragma unroll
        for (int j = 0; j < 8; j++) addrow8(a, v[j]);
    }
    if (p + 3 < c) {
        int s_[4];
#pragma unroll
        for (int j = 0; j < 4; j++) s_[j] = csr[s0 + p + j];
        uint4 v[4];
#pragma unroll
        for (int j = 0; j < 4; j++) v[j] = U[(size_t)s_[j] * 16 + l4];
#pragma unroll
        for (int j = 0; j < 4; j++) addrow8(a, v[j]);
        p += 4;
    }
    for (; p < c; p++) addrow8(a, U[(size_t)csr[s0 + p] * 16 + l4]);

    float dv = dinv[d];
    float4 bb0 = *(const float4*)&bias[l4 * 8];
    float4 bb1 = *(const float4*)&bias[l4 * 8 + 4];
    float r[8];
    r[0] = dv * a[0] + bb0.x; r[1] = dv * a[1] + bb0.y;
    r[2] = dv * a[2] + bb0.z; r[3] = dv * a[3] + bb0.w;
    r[4] = dv * a[4] + bb1.x; r[5] = dv * a[5] + bb1.y;
    r[6] = dv * a[6] + bb1.z; r[7] = dv * a[7] + bb1.w;
    ushort8 hh;
#pragma unroll
    for (int j = 0; j < 8; j++) hh[j] = f2bf(fmaxf(r[j], 0.f));
    *(ushort8*)&yh[(size_t)d * HID + l4 * 8] = hh;
}

// ---- layer-2 gather (quarter-wave, uint4) fused with mean-pool accumulation ----
__global__ void k_gather128p(const unsigned int* __restrict__ ubf, const int* __restrict__ off,
                             const int* __restrict__ indeg, const int* __restrict__ csr,
                             const float* __restrict__ dinv, const float* __restrict__ bias,
                             const int* __restrict__ batch, float* __restrict__ pooledm, int n) {
    __shared__ __align__(16) float part[16][132];   // +4 pad
    __shared__ int bid[16];
    int t = threadIdx.x;
    int lane = t & 63;
    int quad = lane >> 4, l4 = lane & 15;
    int slot = (t >> 6) * 4 + quad;           // 0..15
    int d = blockIdx.x * 16 + slot;
    const uint4* U = (const uint4*)ubf;
    if (d < n) {
        int s0 = off[d], c = indeg[d];
        float a[8] = {0.f, 0.f, 0.f, 0.f, 0.f, 0.f, 0.f, 0.f};
        addrow8(a, U[(size_t)d * 16 + l4]);
        int p = 0;
        for (; p + 7 < c; p += 8) {
            int s_[8];
#pragma unroll
            for (int j = 0; j < 8; j++) s_[j] = csr[s0 + p + j];
            uint4 v[8];
#pragma unroll
            for (int j = 0; j < 8; j++) v[j] = U[(size_t)s_[j] * 16 + l4];
#pragma unroll
            for (int j = 0; j < 8; j++) addrow8(a, v[j]);
        }
        if (p + 3 < c) {
            int s_[4];
#pragma unroll
            for (int j = 0; j < 4; j++) s_[j] = csr[s0 + p + j];
            uint4 v[4];
#pragma unroll
            for (int j = 0; j < 4; j++) v[j] = U[(size_t)s_[j] * 16 + l4];
#pragma unroll
            for (int j = 0; j < 4; j++) addrow8(a, v[j]);
            p += 4;
        }
        for (; p < c; p++) addrow8(a, U[(size_t)csr[s0 + p] * 16 + l4]);

        float dv = dinv[d];
        float4 bb0 = *(const float4*)&bias[l4 * 8];
        float4 bb1 = *(const float4*)&bias[l4 * 8 + 4];
        float4 r0 = {dv * a[0] + bb0.x, dv * a[1] + bb0.y, dv * a[2] + bb0.z, dv * a[3] + bb0.w};
        float4 r1 = {dv * a[4] + bb1.x, dv * a[5] + bb1.y, dv * a[6] + bb1.z, dv * a[7] + bb1.w};
        *(float4*)&part[slot][l4 * 8] = r0;
        *(float4*)&part[slot][l4 * 8 + 4] = r1;
        if (l4 == 0) bid[slot] = batch[d];
    } else {
        if (l4 == 0) bid[slot] = -1;
    }
    __syncthreads();
    if (t < 128) {      // per-feature run reduction over the 16 nodes
        int f = t;
        float acc = 0.f;
        int g = -1;
        for (int j = 0; j < 16; j++) {
            int bj = bid[j];
            if (bj < 0) break;    // tail block: invalid nodes are trailing
            if (bj != g) {
                if (g >= 0) atomicAdd(&pooledm[g * HID + f], acc);
                g = bj; acc = 0.f;
            }
            acc += part[j][f];
        }
        if (g >= 0) atomicAdd(&pooledm[g * HID + f], acc);
    }
}

// -------------------- fused MLP head: fc0 + fc1 + fco --------------------
__global__ void k_head(const float* __restrict__ pooledm, const int* __restrict__ cnt,
                       const float* __restrict__ Wf0, const float* __restrict__ bf0,
                       const float* __restrict__ Wf1, const float* __restrict__ bf1,
                       const float* __restrict__ Wo, const float* __restrict__ bo,
                       float* __restrict__ out) {
    __shared__ float row[128];
    __shared__ float f0[256];
    __shared__ float f1[128];
    int g = blockIdx.x, t = threadIdx.x;   // 256 threads
    if (t < 128) row[t] = pooledm[g * 128 + t] * (1.f / (float)max(cnt[g], 1));
    __syncthreads();
    {
        float acc = 0.f;
#pragma unroll 8
        for (int k = 0; k < 128; k++) acc += row[k] * Wf0[k * 256 + t];
        f0[t] = fmaxf(acc + bf0[t], 0.f);
    }
    __syncthreads();
    if (t < 128) {
        float acc = 0.f;
#pragma unroll 8
        for (int k = 0; k < 256; k++) acc += f0[k] * Wf1[k * 128 + t];
        f1[t] = fmaxf(acc + bf1[t], 0.f);
    }
    __syncthreads();
    if (t < 64) {
        float acc = f1[t] * Wo[t] + f1[t + 64] * Wo[64 + t];
        for (int s = 32; s > 0; s >>= 1) acc += __shfl_down(acc, s);
        if (t == 0) out[g] = acc + bo[0];
    }
}

// -------------------- launch --------------------
extern "C" void kernel_launch(void* const* d_in, const int* in_sizes, int n_in,
                              void* d_out, int out_size, void* d_ws, size_t ws_size,
                              hipStream_t stream) {
    const float* x   = (const float*)d_in[0];
    const int* ei    = (const int*)d_in[1];
    const int* src   = ei;
    const int* dst   = ei + N_EDGES;
    const int* batch = (const int*)d_in[2];
    const float* W0 = (const float*)d_in[3];  const float* b0 = (const float*)d_in[4];
    const float* W1 = (const float*)d_in[5];  const float* b1 = (const float*)d_in[6];
    const float* W2 = (const float*)d_in[7];  const float* b2 = (const float*)d_in[8];
    const float* Wf0 = (const float*)d_in[9];  const float* bf0 = (const float*)d_in[10];
    const float* Wf1 = (const float*)d_in[11]; const float* bf1 = (const float*)d_in[12];
    const float* Wo = (const float*)d_in[13];  const float* bo = (const float*)d_in[14];
    float* out = (float*)d_out;

    char* w = (char*)d_ws;
    size_t o = 0;
    auto take = [&](size_t bytes) -> char* {
        char* p = w + o;
        o += (bytes + 255) & ~(size_t)255;
        return p;
    };
    int* indeg    = (int*)take((size_t)N_NODES * 4);
    int* off      = (int*)take((size_t)N_NODES * 4);
    int* counts   = (int*)take((size_t)N2 * 4);
    int* scT      = (int*)take((size_t)N2 * 4);
    int* bsum     = (int*)take(256 * 4);
    int* bpre     = (int*)take(256 * 4);
    int* csr      = (int*)take((size_t)N_EDGES * 4);
    float* dinv   = (float*)take((size_t)N_NODES * 4);
    int* cnt      = (int*)take((size_t)N_GRAPHS * 4);
    float* xs     = (float*)take((size_t)N_NODES * 16 * 4);
    unsigned short* hbf0 = (unsigned short*)take((size_t)N_NODES * HID * 2);
    unsigned short* hbf1 = (unsigned short*)take((size_t)N_NODES * HID * 2);
    unsigned short* ubf  = (unsigned short*)take((size_t)N_NODES * HID * 2);
    unsigned short* Wt1  = (unsigned short*)take((size_t)HID * HID * 2);
    unsigned short* Wt2  = (unsigned short*)take((size_t)HID * HID * 2);
    float* pooledm= (float*)take((size_t)N_GRAPHS * HID * 4);
    // bstore (6.4MB) aliases ubf (25.6MB): bstore dead after k_bhistx; ubf written later
    unsigned int* bstore = (unsigned int*)ubf;

    // ---- topology: contention-free counting sort by dst bucket ----
    k_hist1<<<NBLK, 256, 0, stream>>>(dst, counts, W1, W2, Wt1, Wt2, cnt, N_EDGES);
    int nb2 = (N2 + 1023) / 1024;
    k_scan1T<<<nb2, 256, 0, stream>>>(counts, scT, bsum, N2);
    k_scan_block<<<1, 256, 0, stream>>>(bsum, bpre, nb2);
    k_scatter<<<NBLK, 256, 0, stream>>>(src, dst, scT, bpre, bstore, pooledm, N_EDGES);
    // fused: histogram + off/dinv/xs + graph counts + csr fill
    k_bhistx<<<NB, 256, 0, stream>>>(bstore, scT, bpre, x, batch, indeg, dinv, xs, off, cnt, csr, N_NODES, N_EDGES);

    // layer 0: fused gather(13-wide) + GEMM -> bf16 h0
    k_gf13<<<(N_NODES + 63) / 64, 256, 0, stream>>>(xs, off, indeg, csr, dinv, W0, b0, hbf0, N_NODES);
    // layer 1: MFMA GEMM + gather (bf16 out)
    k_mfma128<<<(N_NODES + 255) / 256, 256, 0, stream>>>(hbf0, Wt1, dinv, ubf, N_NODES);
    k_gather128<<<(N_NODES + 15) / 16, 256, 0, stream>>>((const unsigned int*)ubf, off, indeg, csr, dinv, b1, hbf1, N_NODES);
    // layer 2: MFMA GEMM + gather fused with mean-pool accumulation
    k_mfma128<<<(N_NODES + 255) / 256, 256, 0, stream>>>(hbf1, Wt2, dinv, ubf, N_NODES);
    k_gather128p<<<(N_NODES + 15) / 16, 256, 0, stream>>>((const unsigned int*)ubf, off, indeg, csr, dinv, b2, batch, pooledm, N_NODES);

    // fused MLP head
    k_head<<<N_GRAPHS, 256, 0, stream>>>(pooledm, cnt, Wf0, bf0, Wf1, bf1, Wo, bo, out);
}